// Round 20
// baseline (322.043 us; speedup 1.0000x reference)
//
#include <hip/hip_runtime.h>
#include <hip/hip_bf16.h>
#include <math.h>

typedef unsigned short u16;
typedef __bf16 bf16x8 __attribute__((ext_vector_type(8)));
typedef __bf16 bf16x4 __attribute__((ext_vector_type(4)));
typedef float  f32x4  __attribute__((ext_vector_type(4)));

#define DIMC 256
#define QSZ  56
#define WSZ  7
#define SSZ  3
#define LWIN 49
#define NWIN 64
#define HW   3136          // 56*56
#define NTOK 50176         // 16*3136
#define FFWD 1024
#define FCH  25088         // NTOK/2 ffn chunk rows
#define PLS  68            // Pl row stride u16: 136 B (b64-aligned); 8*49*68*2 = 53,312 B

__device__ __forceinline__ u16 f2bu(float f) {
    __hip_bfloat16 h = __float2bfloat16(f);
    return __builtin_bit_cast(u16, h);
}
__device__ __forceinline__ float bu2f(u16 u) {
    unsigned v = (unsigned)u << 16;
    return __builtin_bit_cast(float, v);
}
__device__ __forceinline__ void gload_lds16(const void* g, void* l) {
    __builtin_amdgcn_global_load_lds((const __attribute__((address_space(1))) void*)g,
                                     (__attribute__((address_space(3))) void*)l, 16, 0, 0);
}

// XCD-bijective swizzle (m204): nwg % 8 == 0 required.
__device__ __forceinline__ int xcd_swz(int flat, int nwg) {
    int q = nwg >> 3;
    return (flat & 7) * q + (flat >> 3);
}

__device__ __forceinline__ int region_of(int h) {
    return (h < 49) ? 0 : ((h < 53) ? 1 : 2);
}

// partitioned row m = ((b*64 + wi)*49 + p) -> flat token index (with roll by -3)
__device__ __forceinline__ int row2tok(int m) {
    int b  = m / (NWIN * LWIN);
    int r  = m - b * (NWIN * LWIN);
    int wi = r / LWIN;
    int p  = r - wi * LWIN;
    int wh = wi >> 3, ww = wi & 7;
    int ph = p / 7,   pw = p - ph * 7;
    int hr = wh * 7 + ph, wr = ww * 7 + pw;
    int hs = hr + SSZ; if (hs >= QSZ) hs -= QSZ;
    int ws2 = wr + SSZ; if (ws2 >= QSZ) ws2 -= QSZ;
    return b * HW + hs * QSZ + ws2;
}

// ---------------- merged weight transpose + bf16 convert (4 weights) ----------
__device__ __forceinline__ void wconv_body(const float* __restrict__ W,
        u16* __restrict__ Wt, int K, int N, int bx, int by, int t) {
    __shared__ float tile[32][33];
    int k0 = bx * 32, n0 = by * 32;
    int tx = t & 31, ty = t >> 5;
    for (int kk = ty; kk < 32; kk += 8)
        tile[kk][tx] = W[(size_t)(k0 + kk) * N + n0 + tx];
    __syncthreads();
    for (int nn = ty; nn < 32; nn += 8)
        Wt[(size_t)(n0 + nn) * K + k0 + tx] = f2bu(tile[tx][nn]);
}

__global__ __launch_bounds__(256) void k_wconv_all(
        const float* __restrict__ qkv_w, u16* __restrict__ wqt,
        const float* __restrict__ proj_w, u16* __restrict__ wpt,
        const float* __restrict__ ffn_w1, u16* __restrict__ w1t,
        const float* __restrict__ ffn_w2, u16* __restrict__ w2t) {
    int b = blockIdx.x, t = threadIdx.x;
    if (b < 192)        wconv_body(qkv_w, wqt, 256, 768, b & 7, b >> 3, t);
    else if (b < 256) { b -= 192; wconv_body(proj_w, wpt, 256, 256,  b & 7, b >> 3, t); }
    else if (b < 512) { b -= 256; wconv_body(ffn_w1, w1t, 256, 1024, b & 7, b >> 3, t); }
    else              { b -= 512; wconv_body(ffn_w2, w2t, 1024, 256, b & 31, b >> 5, t); }
}

// ---------------- K1: BCHW -> token-major transpose + LN1 -> bf16 -------------
__global__ __launch_bounds__(256) void k_ln1(const float* __restrict__ x,
        const float* __restrict__ g, const float* __restrict__ be,
        u16* __restrict__ hln) {
    __shared__ float tile[32][257];
    __shared__ float msh[32], rsh[32];
    int blk = blockIdx.x;            // 16 * 98
    int b   = blk / 98;
    int hw0 = (blk - b * 98) * 32;
    int t   = threadIdx.x;
    int tx  = t & 31, ty = t >> 5;
    for (int c = ty; c < 256; c += 8)
        tile[tx][c] = x[(size_t)(b * 256 + c) * HW + hw0 + tx];
    __syncthreads();
    int row = t >> 3, sub = t & 7;
    float s = 0.f, sq = 0.f;
    for (int c = sub * 32; c < sub * 32 + 32; ++c) {
        float v = tile[row][c]; s += v; sq += v * v;
    }
    for (int o = 4; o; o >>= 1) { s += __shfl_down(s, o, 8); sq += __shfl_down(sq, o, 8); }
    if (sub == 0) {
        float m   = s * (1.f / 256.f);
        float var = sq * (1.f / 256.f) - m * m;
        msh[row] = m; rsh[row] = rsqrtf(var + 1e-5f);
    }
    __syncthreads();
    float gg = g[t], bb = be[t];
    for (int r2 = 0; r2 < 32; ++r2) {
        float v = tile[r2][t];
        hln[(size_t)(b * HW + hw0 + r2) * 256 + t] = f2bu((v - msh[r2]) * rsh[r2] * gg + bb);
    }
}

// ---------------- LN2 + residual: x1 = proj_out + transpose(x); h2 = LN(x1) ---
__global__ __launch_bounds__(256) void k_ln2t(const float* __restrict__ x,
        u16* __restrict__ x1b, const float* __restrict__ g,
        const float* __restrict__ be, u16* __restrict__ h2) {
    __shared__ float tile[32][257];
    __shared__ float msh[32], rsh[32];
    int blk = blockIdx.x;            // 16 * 98
    int b   = blk / 98;
    int hw0 = (blk - b * 98) * 32;
    int t   = threadIdx.x;
    int tx  = t & 31, ty = t >> 5;
    for (int c = ty; c < 256; c += 8)
        tile[tx][c] = x[(size_t)(b * 256 + c) * HW + hw0 + tx];
    __syncthreads();
    size_t base = (size_t)b * HW + hw0;
    for (int r2 = 0; r2 < 32; ++r2) {
        float v = tile[r2][t] + bu2f(x1b[(base + r2) * 256 + t]);
        tile[r2][t] = v;
        x1b[(base + r2) * 256 + t] = f2bu(v);
    }
    __syncthreads();
    int row = t >> 3, sub = t & 7;
    float s = 0.f, sq = 0.f;
    for (int c = sub * 32; c < sub * 32 + 32; ++c) {
        float v = tile[row][c]; s += v; sq += v * v;
    }
    for (int o = 4; o; o >>= 1) { s += __shfl_down(s, o, 8); sq += __shfl_down(sq, o, 8); }
    if (sub == 0) {
        float m   = s * (1.f / 256.f);
        float var = sq * (1.f / 256.f) - m * m;
        msh[row] = m; rsh[row] = rsqrtf(var + 1e-5f);
    }
    __syncthreads();
    float gg = g[t], bb = be[t];
    for (int r2 = 0; r2 < 32; ++r2) {
        float v = tile[r2][t];
        h2[(base + r2) * 256 + t] = f2bu((v - msh[r2]) * rsh[r2] * gg + bb);
    }
}

// ---------------- MFMA GEMM, 256x128 tile, 512 thr (qkv / ffn1) ---------------
// R13-verified loop + T1 XCD grid (verified R17: -28 us).
template<int MODE>
__global__ __launch_bounds__(512) void k_mgemm256(
        const u16* __restrict__ A, const u16* __restrict__ Bt,
        const float* __restrict__ bias, void* __restrict__ Cv, int K, int N,
        int gy) {
    __shared__ __align__(16) u16 As[2][256 * 32];
    __shared__ __align__(16) u16 Bs[2][128 * 32];
    const int swz = xcd_swz(blockIdx.x, gridDim.x);
    const int mb = swz / gy, nb = swz - mb * gy;
    const int m0 = mb * 256, n0 = nb * 128;
    const int t = threadIdx.x, lane = t & 63;
    const int wv = t >> 6, wr = wv >> 1, wc = wv & 1;

    const int kc = (t & 3) ^ ((t >> 3) & 3);
    int ar0 = m0 + (t >> 2), ar1 = m0 + 128 + (t >> 2);
    if (MODE == 0) { ar0 = row2tok(ar0); ar1 = row2tok(ar1); }
    const u16* gA0 = A  + (size_t)ar0 * K + kc * 8;
    const u16* gA1 = A  + (size_t)ar1 * K + kc * 8;
    const u16* gB0 = Bt + (size_t)(n0 + (t >> 2)) * K + kc * 8;

    f32x4 acc[4][4] = {};
    const int ra = wr * 64 + (lane & 15);
    const int rb = wc * 64 + (lane & 15);
    const int kos = (((lane >> 4) ^ (lane >> 1)) & 3) * 8;
    const int nIter = K >> 5;

    gload_lds16(gA0, As[0] + t * 8);
    gload_lds16(gA1, As[0] + 4096 + t * 8);
    gload_lds16(gB0, Bs[0] + t * 8);

    int cur = 0;
    for (int it = 0; it < nIter; ++it) {
        if (it + 1 < nIter) {
            const int k1 = (it + 1) << 5;
            gload_lds16(gA0 + k1, As[cur ^ 1] + t * 8);
            gload_lds16(gA1 + k1, As[cur ^ 1] + 4096 + t * 8);
            gload_lds16(gB0 + k1, Bs[cur ^ 1] + t * 8);
            asm volatile("s_waitcnt vmcnt(3)" ::: "memory");
        } else {
            asm volatile("s_waitcnt vmcnt(0)" ::: "memory");
        }
        __builtin_amdgcn_s_barrier();
        __builtin_amdgcn_sched_barrier(0);
        bf16x8 af[4], bfr[4];
#pragma unroll
        for (int i = 0; i < 4; ++i)
            af[i] = *(const bf16x8*)(As[cur] + (ra + i * 16) * 32 + kos);
#pragma unroll
        for (int j = 0; j < 4; ++j)
            bfr[j] = *(const bf16x8*)(Bs[cur] + (rb + ((j & 1) * 16 + (j >> 1) * 32)) * 32 + kos);
        asm volatile("s_waitcnt lgkmcnt(0)" ::: "memory");
        __builtin_amdgcn_sched_barrier(0);
        __builtin_amdgcn_s_barrier();
#pragma unroll
        for (int i = 0; i < 4; ++i)
#pragma unroll
            for (int j = 0; j < 4; ++j)
                acc[i][j] = __builtin_amdgcn_mfma_f32_16x16x32_bf16(af[i], bfr[j], acc[i][j], 0, 0, 0);
        cur ^= 1;
    }

    const int rowb = m0 + wr * 64 + ((lane >> 4) * 4);
    u16* Cb = (u16*)Cv;
#pragma unroll
    for (int j = 0; j < 4; ++j) {
        int col = n0 + wc * 64 + ((j & 1) * 16 + (j >> 1) * 32) + (lane & 15);
        float bj = bias[col];
#pragma unroll
        for (int i = 0; i < 4; ++i) {
            int rw = rowb + i * 16;
#pragma unroll
            for (int r = 0; r < 4; ++r) {
                float v = acc[i][j][r] + bj;
                if (MODE == 2) v = fmaxf(v, 0.f);
                Cb[(size_t)(rw + r) * N + col] = f2bu(v);
            }
        }
    }
}

// ---------------- MFMA GEMM, 128x128 tile, 256 thr (ffn2) ---------------------
template<int MODE>
__global__ __launch_bounds__(256) void k_mgemm128(
        const u16* __restrict__ A, const u16* __restrict__ Bt,
        const float* __restrict__ bias, void* __restrict__ Cv,
        int K, int N, const void* __restrict__ extra,
        const float* __restrict__ extra2, int grow0, int gy) {
    __shared__ __align__(16) u16 As[2][128 * 32];
    __shared__ __align__(16) u16 Bs[2][128 * 32];
    const int swz = xcd_swz(blockIdx.x, gridDim.x);
    const int mb = swz / gy, nb = swz - mb * gy;
    const int m0 = mb * 128, n0 = nb * 128;
    const int t = threadIdx.x, lane = t & 63;
    const int wv = t >> 6, wr = wv >> 1, wc = wv & 1;

    const int kc = (t & 3) ^ ((t >> 3) & 3);
    const u16* gA0 = A  + (size_t)(m0 + (t >> 2)) * K + kc * 8;
    const u16* gA1 = A  + (size_t)(m0 + 64 + (t >> 2)) * K + kc * 8;
    const u16* gB0 = Bt + (size_t)(n0 + (t >> 2)) * K + kc * 8;
    const u16* gB1 = Bt + (size_t)(n0 + 64 + (t >> 2)) * K + kc * 8;

    f32x4 acc[4][4] = {};
    const int ra = wr * 64 + (lane & 15);
    const int rb = wc * 64 + (lane & 15);
    const int kos = (((lane >> 4) ^ (lane >> 1)) & 3) * 8;
    const int nIter = K >> 5;

    gload_lds16(gA0, As[0] + t * 8);
    gload_lds16(gA1, As[0] + 2048 + t * 8);
    gload_lds16(gB0, Bs[0] + t * 8);
    gload_lds16(gB1, Bs[0] + 2048 + t * 8);

    int cur = 0;
    for (int it = 0; it < nIter; ++it) {
        if (it + 1 < nIter) {
            const int k1 = (it + 1) << 5;
            gload_lds16(gA0 + k1, As[cur ^ 1] + t * 8);
            gload_lds16(gA1 + k1, As[cur ^ 1] + 2048 + t * 8);
            gload_lds16(gB0 + k1, Bs[cur ^ 1] + t * 8);
            gload_lds16(gB1 + k1, Bs[cur ^ 1] + 2048 + t * 8);
            asm volatile("s_waitcnt vmcnt(4)" ::: "memory");
        } else {
            asm volatile("s_waitcnt vmcnt(0)" ::: "memory");
        }
        __builtin_amdgcn_s_barrier();
        __builtin_amdgcn_sched_barrier(0);
        bf16x8 af[4], bfr[4];
#pragma unroll
        for (int i = 0; i < 4; ++i)
            af[i] = *(const bf16x8*)(As[cur] + (ra + i * 16) * 32 + kos);
#pragma unroll
        for (int j = 0; j < 4; ++j)
            bfr[j] = *(const bf16x8*)(Bs[cur] + (rb + j * 16) * 32 + kos);
        asm volatile("s_waitcnt lgkmcnt(0)" ::: "memory");
        __builtin_amdgcn_sched_barrier(0);
        __builtin_amdgcn_s_barrier();
#pragma unroll
        for (int i = 0; i < 4; ++i)
#pragma unroll
            for (int j = 0; j < 4; ++j)
                acc[i][j] = __builtin_amdgcn_mfma_f32_16x16x32_bf16(af[i], bfr[j], acc[i][j], 0, 0, 0);
        cur ^= 1;
    }

    const int colb = n0 + wc * 64 + (lane & 15);
    const int rowb = m0 + wr * 64 + ((lane >> 4) * 4);

    float* C = (float*)Cv;
    const u16* xr = (const u16*)extra;       // x1 bf16
#pragma unroll
    for (int j = 0; j < 4; ++j) {
        int col = colb + j * 16;
        float bj = bias[col], lj = extra2[col];
#pragma unroll
        for (int i = 0; i < 4; ++i) {
            int g  = grow0 + rowb + i * 16;   // 4-row pack never crosses batch
            int b  = g / HW, hw = g - b * HW;
            f32x4 o;
#pragma unroll
            for (int r = 0; r < 4; ++r)
                o[r] = bu2f(xr[(size_t)(g + r) * 256 + col]) + lj * (acc[i][j][r] + bj);
            *(f32x4*)(C + ((size_t)(b * 256 + col)) * HW + hw) = o;
        }
    }
}

// ---------------- fused attention + proj: one BLOCK per window ----------------
// R18 structure; Pl stride 68 u16 (136 B, b64-aligned) -> LDS 53,312 B ->
// 3 blocks/CU. PV A-fragment rows CLAMPED to <=48 (precedented-safe: same
// pattern as the QK^T clamp since R5; clamped lanes feed only discarded output
// rows, and all reads stay within the wave's own Pl). Fragments assembled from
// two bf16x4 (ds_read_b64) loads — bf16-typed LDS reads, the pattern proven
// safe everywhere in this kernel (avoids the R19 u32/u16 aliasing bug).
__global__ __launch_bounds__(512, 6) void k_attnproj(const u16* __restrict__ qkv,
        const u16* __restrict__ wpt, const float* __restrict__ pbias,
        u16* __restrict__ x1b) {
    __shared__ __align__(16) u16 U[8 * LWIN * PLS];   // 53,312 B
    const int wv = threadIdx.x >> 6, lane = threadIdx.x & 63;
    const int win = blockIdx.x, head = wv, wi = win & 63;
    const int rowbase = win * LWIN;
    const int g = lane >> 4, c = lane & 15, ko = g * 8;
    const u16* qb = qkv + (size_t)rowbase * 768 + head * 32;
    u16* pl = U + wv * (LWIN * PLS);

    bf16x8 vb[2][2];
#pragma unroll
    for (int j2 = 0; j2 < 2; ++j2) {
        int d = j2 * 16 + c;
#pragma unroll
        for (int h = 0; h < 2; ++h)
#pragma unroll
            for (int tt = 0; tt < 8; ++tt) {
                int k = h * 32 + ko + tt;
                u16 val = (k < LWIN) ? qb[(size_t)k * 768 + 512 + d] : (u16)0;
                vb[j2][h][tt] = __builtin_bit_cast(__bf16, val);
            }
    }

    bf16x8 qf[4], kf[4];
#pragma unroll
    for (int i = 0; i < 4; ++i) {
        int r0 = i * 16 + c; if (r0 > 48) r0 = 48;
        qf[i] = *(const bf16x8*)(qb + (size_t)r0 * 768 + ko);
        kf[i] = *(const bf16x8*)(qb + (size_t)r0 * 768 + 256 + ko);
    }
    f32x4 s[4][4] = {};
    __builtin_amdgcn_s_setprio(1);
#pragma unroll
    for (int i = 0; i < 4; ++i)
#pragma unroll
        for (int j = 0; j < 4; ++j)
            s[i][j] = __builtin_amdgcn_mfma_f32_16x16x32_bf16(qf[i], kf[j], s[i][j], 0, 0, 0);
    __builtin_amdgcn_s_setprio(0);

    const int wh7 = (wi >> 3) * 7, ww7 = (wi & 7) * 7;
    int idj[4]; bool jok[4];
#pragma unroll
    for (int j = 0; j < 4; ++j) {
        int col = j * 16 + c;
        jok[j] = col < LWIN;
        int p = jok[j] ? col : 48;
        idj[j] = region_of(wh7 + p / 7) * 3 + region_of(ww7 + p % 7);
    }
#pragma unroll
    for (int i = 0; i < 4; ++i) {
#pragma unroll
        for (int r = 0; r < 4; ++r) {
            int row = i * 16 + g * 4 + r;
            int p = row < LWIN ? row : 48;
            int idi = region_of(wh7 + p / 7) * 3 + region_of(ww7 + p % 7);
            float mx = -1e30f;
#pragma unroll
            for (int j = 0; j < 4; ++j) {
                float tv = jok[j] ? fmaf(s[i][j][r], 0.17677669529663687f,
                                         (idi == idj[j]) ? 0.f : -100.f)
                                  : -1e30f;
                s[i][j][r] = tv;
                mx = fmaxf(mx, tv);
            }
            for (int o = 8; o; o >>= 1) mx = fmaxf(mx, __shfl_xor(mx, o));
            float ps = 0.f;
#pragma unroll
            for (int j = 0; j < 4; ++j) {
                float e = __expf(s[i][j][r] - mx);
                s[i][j][r] = e; ps += e;
            }
            for (int o = 8; o; o >>= 1) ps += __shfl_xor(ps, o);
            float inv = 1.f / ps;
            if (row < LWIN) {
#pragma unroll
                for (int j = 0; j < 4; ++j)
                    pl[row * PLS + j * 16 + c] = f2bu(s[i][j][r] * inv);
            }
        }
    }
    // per-wave pl: compiler-inserted lgkmcnt orders write->read within the wave

    // --- O = P V: rows clamped <=48, fragments via two b64 bf16x4 loads ---
    f32x4 o[4][2] = {};
    __builtin_amdgcn_s_setprio(1);
#pragma unroll
    for (int i = 0; i < 4; ++i) {
        int rowA = i * 16 + c; if (rowA > 48) rowA = 48;
        const u16* pr = pl + rowA * PLS + ko;
        bf16x4 a0 = *(const bf16x4*)(pr);
        bf16x4 a1 = *(const bf16x4*)(pr + 4);
        bf16x4 b0 = *(const bf16x4*)(pr + 32);
        bf16x4 b1 = *(const bf16x4*)(pr + 36);
        bf16x8 pa0 = __builtin_shufflevector(a0, a1, 0, 1, 2, 3, 4, 5, 6, 7);
        bf16x8 pa1 = __builtin_shufflevector(b0, b1, 0, 1, 2, 3, 4, 5, 6, 7);
#pragma unroll
        for (int j2 = 0; j2 < 2; ++j2) {
            o[i][j2] = __builtin_amdgcn_mfma_f32_16x16x32_bf16(pa0, vb[j2][0], o[i][j2], 0, 0, 0);
            o[i][j2] = __builtin_amdgcn_mfma_f32_16x16x32_bf16(pa1, vb[j2][1], o[i][j2], 0, 0, 0);
        }
    }
    __builtin_amdgcn_s_setprio(0);

    __syncthreads();        // all waves done reading Pl -> U reusable as o_t

    // --- weight slice -> registers (no swizzle: regs have no banks) ---
    bf16x8 wreg[8][2];
#pragma unroll
    for (int it = 0; it < 8; ++it)
#pragma unroll
        for (int j2 = 0; j2 < 2; ++j2)
            wreg[it][j2] = *(const bf16x8*)(wpt +
                (size_t)(wv * 32 + j2 * 16 + c) * 256 + it * 32 + ko);

    // --- o_t = U (64 x 264: row stride 528 B -> 2-way banks, free) ---
    u16* o_t = U;
#pragma unroll
    for (int i = 0; i < 4; ++i)
#pragma unroll
        for (int r = 0; r < 4; ++r) {
            int row = i * 16 + g * 4 + r;
            if (row < LWIN) {
#pragma unroll
                for (int j2 = 0; j2 < 2; ++j2)
                    o_t[row * 264 + head * 32 + j2 * 16 + c] = f2bu(o[i][j2][r]);
            }
        }
    __syncthreads();        // o_t complete (rows >= 49 stale-garbage: discarded)

    // --- proj: 8 x {4 ds_read + 8 MFMA}, no barriers, weights in regs ---
    f32x4 acc2[4][2] = {};
#pragma unroll
    for (int it = 0; it < 8; ++it) {
        bf16x8 af[4];
#pragma unroll
        for (int i = 0; i < 4; ++i)
            af[i] = *(const bf16x8*)(o_t + (i * 16 + c) * 264 + it * 32 + ko);
        __builtin_amdgcn_s_setprio(1);
#pragma unroll
        for (int i = 0; i < 4; ++i)
#pragma unroll
            for (int j2 = 0; j2 < 2; ++j2)
                acc2[i][j2] = __builtin_amdgcn_mfma_f32_16x16x32_bf16(af[i], wreg[it][j2], acc2[i][j2], 0, 0, 0);
        __builtin_amdgcn_s_setprio(0);
    }

    // --- epilogue: scatter to x1b (proj_out) via row2tok, + bias ---
#pragma unroll
    for (int j2 = 0; j2 < 2; ++j2) {
        int col = wv * 32 + j2 * 16 + c;
        float bj = pbias[col];
#pragma unroll
        for (int i = 0; i < 4; ++i)
#pragma unroll
            for (int r = 0; r < 4; ++r) {
                int row = i * 16 + g * 4 + r;
                if (row < LWIN) {
                    int tok = row2tok(rowbase + row);
                    x1b[(size_t)tok * 256 + col] = f2bu(acc2[i][j2][r] + bj);
                }
            }
    }
}

extern "C" void kernel_launch(void* const* d_in, const int* in_sizes, int n_in,
                              void* d_out, int out_size, void* d_ws, size_t ws_size,
                              hipStream_t stream) {
    const float* x      = (const float*)d_in[0];
    const float* ln1_g  = (const float*)d_in[1];
    const float* ln1_b  = (const float*)d_in[2];
    const float* ln2_g  = (const float*)d_in[3];
    const float* ln2_b  = (const float*)d_in[4];
    const float* qkv_w  = (const float*)d_in[5];
    const float* qkv_b  = (const float*)d_in[6];
    const float* proj_w = (const float*)d_in[7];
    const float* proj_b = (const float*)d_in[8];
    const float* ffn_w1 = (const float*)d_in[9];
    const float* ffn_b1 = (const float*)d_in[10];
    const float* ffn_w2 = (const float*)d_in[11];
    const float* ffn_b2 = (const float*)d_in[12];
    const float* lscale = (const float*)d_in[13];

    // workspace: total 104,333,312 B (layout unchanged since R6)
    char* wsb = (char*)d_ws;
    u16* wqt  = (u16*)(wsb);
    u16* wpt  = (u16*)(wsb + 393216);
    u16* w1t  = (u16*)(wsb + 524288);
    u16* w2t  = (u16*)(wsb + 1048576);
    u16* P    = (u16*)(wsb + 1572864);
    char* Qb  = wsb + 27262976;
    u16* qkvb = (u16*)Qb;
    u16* x1b  = (u16*)Qb;
    u16* f1c  = (u16*)(Qb + 25690112);

    k_wconv_all<<<768, 256, 0, stream>>>(qkv_w, wqt, proj_w, wpt, ffn_w1, w1t, ffn_w2, w2t);

    k_ln1<<<16 * 98, 256, 0, stream>>>(x, ln1_g, ln1_b, P);
    // qkv: 196 m-blocks x 6 n-blocks, XCD-swizzled 1-D grid (1176 % 8 == 0)
    k_mgemm256<0><<<1176, 512, 0, stream>>>(P, wqt, qkv_b, qkvb, 256, 768, 6);
    // fused attention + proj -> proj_out (x1b, token-scattered bf16)
    k_attnproj<<<1024, 512, 0, stream>>>(qkvb, wpt, proj_b, x1b);
    // x1 = proj_out + transpose(x) (in-place), h2 = LN2(x1) -> P
    k_ln2t<<<16 * 98, 256, 0, stream>>>(x, x1b, ln2_g, ln2_b, P);
    for (int c = 0; c < 2; ++c) {
        // ffn1: 98 x 8 = 784 (784 % 8 == 0)
        k_mgemm256<2><<<784, 512, 0, stream>>>(P + (size_t)c * FCH * 256, w1t, ffn_b1,
                                               f1c, 256, 1024, 8);
        // ffn2: 196 x 2 = 392 (392 % 8 == 0)
        k_mgemm128<3><<<392, 256, 0, stream>>>(f1c, w2t, ffn_b2, d_out, 1024, 256,
                                               x1b, lscale, c * FCH, 2);
    }
}

// Round 21
// 241.664 us; speedup vs baseline: 1.3326x; 1.3326x over previous
//
#include <hip/hip_runtime.h>
#include <hip/hip_bf16.h>
#include <math.h>

typedef unsigned short u16;
typedef __bf16 bf16x8 __attribute__((ext_vector_type(8)));
typedef __bf16 bf16x4 __attribute__((ext_vector_type(4)));
typedef float  f32x4  __attribute__((ext_vector_type(4)));

#define DIMC 256
#define QSZ  56
#define WSZ  7
#define SSZ  3
#define LWIN 49
#define NWIN 64
#define HW   3136          // 56*56
#define NTOK 50176         // 16*3136
#define FFWD 1024
#define FCH  25088         // NTOK/2 ffn chunk rows
#define PLS  68            // Pl row stride u16: 136 B (b64-aligned); 8*49*68*2 = 53,312 B

__device__ __forceinline__ u16 f2bu(float f) {
    __hip_bfloat16 h = __float2bfloat16(f);
    return __builtin_bit_cast(u16, h);
}
__device__ __forceinline__ float bu2f(u16 u) {
    unsigned v = (unsigned)u << 16;
    return __builtin_bit_cast(float, v);
}
__device__ __forceinline__ void gload_lds16(const void* g, void* l) {
    __builtin_amdgcn_global_load_lds((const __attribute__((address_space(1))) void*)g,
                                     (__attribute__((address_space(3))) void*)l, 16, 0, 0);
}

// XCD-bijective swizzle (m204): nwg % 8 == 0 required.
__device__ __forceinline__ int xcd_swz(int flat, int nwg) {
    int q = nwg >> 3;
    return (flat & 7) * q + (flat >> 3);
}

__device__ __forceinline__ int region_of(int h) {
    return (h < 49) ? 0 : ((h < 53) ? 1 : 2);
}

// partitioned row m = ((b*64 + wi)*49 + p) -> flat token index (with roll by -3)
__device__ __forceinline__ int row2tok(int m) {
    int b  = m / (NWIN * LWIN);
    int r  = m - b * (NWIN * LWIN);
    int wi = r / LWIN;
    int p  = r - wi * LWIN;
    int wh = wi >> 3, ww = wi & 7;
    int ph = p / 7,   pw = p - ph * 7;
    int hr = wh * 7 + ph, wr = ww * 7 + pw;
    int hs = hr + SSZ; if (hs >= QSZ) hs -= QSZ;
    int ws2 = wr + SSZ; if (ws2 >= QSZ) ws2 -= QSZ;
    return b * HW + hs * QSZ + ws2;
}

// ---------------- merged weight transpose + bf16 convert (4 weights) ----------
__device__ __forceinline__ void wconv_body(const float* __restrict__ W,
        u16* __restrict__ Wt, int K, int N, int bx, int by, int t) {
    __shared__ float tile[32][33];
    int k0 = bx * 32, n0 = by * 32;
    int tx = t & 31, ty = t >> 5;
    for (int kk = ty; kk < 32; kk += 8)
        tile[kk][tx] = W[(size_t)(k0 + kk) * N + n0 + tx];
    __syncthreads();
    for (int nn = ty; nn < 32; nn += 8)
        Wt[(size_t)(n0 + nn) * K + k0 + tx] = f2bu(tile[tx][nn]);
}

__global__ __launch_bounds__(256) void k_wconv_all(
        const float* __restrict__ qkv_w, u16* __restrict__ wqt,
        const float* __restrict__ proj_w, u16* __restrict__ wpt,
        const float* __restrict__ ffn_w1, u16* __restrict__ w1t,
        const float* __restrict__ ffn_w2, u16* __restrict__ w2t) {
    int b = blockIdx.x, t = threadIdx.x;
    if (b < 192)        wconv_body(qkv_w, wqt, 256, 768, b & 7, b >> 3, t);
    else if (b < 256) { b -= 192; wconv_body(proj_w, wpt, 256, 256,  b & 7, b >> 3, t); }
    else if (b < 512) { b -= 256; wconv_body(ffn_w1, w1t, 256, 1024, b & 7, b >> 3, t); }
    else              { b -= 512; wconv_body(ffn_w2, w2t, 1024, 256, b & 31, b >> 5, t); }
}

// ---------------- K1: BCHW -> token-major transpose + LN1 -> bf16 -------------
__global__ __launch_bounds__(256) void k_ln1(const float* __restrict__ x,
        const float* __restrict__ g, const float* __restrict__ be,
        u16* __restrict__ hln) {
    __shared__ float tile[32][257];
    __shared__ float msh[32], rsh[32];
    int blk = blockIdx.x;            // 16 * 98
    int b   = blk / 98;
    int hw0 = (blk - b * 98) * 32;
    int t   = threadIdx.x;
    int tx  = t & 31, ty = t >> 5;
    for (int c = ty; c < 256; c += 8)
        tile[tx][c] = x[(size_t)(b * 256 + c) * HW + hw0 + tx];
    __syncthreads();
    int row = t >> 3, sub = t & 7;
    float s = 0.f, sq = 0.f;
    for (int c = sub * 32; c < sub * 32 + 32; ++c) {
        float v = tile[row][c]; s += v; sq += v * v;
    }
    for (int o = 4; o; o >>= 1) { s += __shfl_down(s, o, 8); sq += __shfl_down(sq, o, 8); }
    if (sub == 0) {
        float m   = s * (1.f / 256.f);
        float var = sq * (1.f / 256.f) - m * m;
        msh[row] = m; rsh[row] = rsqrtf(var + 1e-5f);
    }
    __syncthreads();
    float gg = g[t], bb = be[t];
    for (int r2 = 0; r2 < 32; ++r2) {
        float v = tile[r2][t];
        hln[(size_t)(b * HW + hw0 + r2) * 256 + t] = f2bu((v - msh[r2]) * rsh[r2] * gg + bb);
    }
}

// ---------------- LN2 + residual: x1 = proj_out + transpose(x); h2 = LN(x1) ---
__global__ __launch_bounds__(256) void k_ln2t(const float* __restrict__ x,
        u16* __restrict__ x1b, const float* __restrict__ g,
        const float* __restrict__ be, u16* __restrict__ h2) {
    __shared__ float tile[32][257];
    __shared__ float msh[32], rsh[32];
    int blk = blockIdx.x;            // 16 * 98
    int b   = blk / 98;
    int hw0 = (blk - b * 98) * 32;
    int t   = threadIdx.x;
    int tx  = t & 31, ty = t >> 5;
    for (int c = ty; c < 256; c += 8)
        tile[tx][c] = x[(size_t)(b * 256 + c) * HW + hw0 + tx];
    __syncthreads();
    size_t base = (size_t)b * HW + hw0;
    for (int r2 = 0; r2 < 32; ++r2) {
        float v = tile[r2][t] + bu2f(x1b[(base + r2) * 256 + t]);
        tile[r2][t] = v;
        x1b[(base + r2) * 256 + t] = f2bu(v);
    }
    __syncthreads();
    int row = t >> 3, sub = t & 7;
    float s = 0.f, sq = 0.f;
    for (int c = sub * 32; c < sub * 32 + 32; ++c) {
        float v = tile[row][c]; s += v; sq += v * v;
    }
    for (int o = 4; o; o >>= 1) { s += __shfl_down(s, o, 8); sq += __shfl_down(sq, o, 8); }
    if (sub == 0) {
        float m   = s * (1.f / 256.f);
        float var = sq * (1.f / 256.f) - m * m;
        msh[row] = m; rsh[row] = rsqrtf(var + 1e-5f);
    }
    __syncthreads();
    float gg = g[t], bb = be[t];
    for (int r2 = 0; r2 < 32; ++r2) {
        float v = tile[r2][t];
        h2[(base + r2) * 256 + t] = f2bu((v - msh[r2]) * rsh[r2] * gg + bb);
    }
}

// ---------------- MFMA GEMM, 256x128 tile, 512 thr (qkv / ffn1) ---------------
// R13-verified loop + T1 XCD grid (verified R17: -28 us).
template<int MODE>
__global__ __launch_bounds__(512) void k_mgemm256(
        const u16* __restrict__ A, const u16* __restrict__ Bt,
        const float* __restrict__ bias, void* __restrict__ Cv, int K, int N,
        int gy) {
    __shared__ __align__(16) u16 As[2][256 * 32];
    __shared__ __align__(16) u16 Bs[2][128 * 32];
    const int swz = xcd_swz(blockIdx.x, gridDim.x);
    const int mb = swz / gy, nb = swz - mb * gy;
    const int m0 = mb * 256, n0 = nb * 128;
    const int t = threadIdx.x, lane = t & 63;
    const int wv = t >> 6, wr = wv >> 1, wc = wv & 1;

    const int kc = (t & 3) ^ ((t >> 3) & 3);
    int ar0 = m0 + (t >> 2), ar1 = m0 + 128 + (t >> 2);
    if (MODE == 0) { ar0 = row2tok(ar0); ar1 = row2tok(ar1); }
    const u16* gA0 = A  + (size_t)ar0 * K + kc * 8;
    const u16* gA1 = A  + (size_t)ar1 * K + kc * 8;
    const u16* gB0 = Bt + (size_t)(n0 + (t >> 2)) * K + kc * 8;

    f32x4 acc[4][4] = {};
    const int ra = wr * 64 + (lane & 15);
    const int rb = wc * 64 + (lane & 15);
    const int kos = (((lane >> 4) ^ (lane >> 1)) & 3) * 8;
    const int nIter = K >> 5;

    gload_lds16(gA0, As[0] + t * 8);
    gload_lds16(gA1, As[0] + 4096 + t * 8);
    gload_lds16(gB0, Bs[0] + t * 8);

    int cur = 0;
    for (int it = 0; it < nIter; ++it) {
        if (it + 1 < nIter) {
            const int k1 = (it + 1) << 5;
            gload_lds16(gA0 + k1, As[cur ^ 1] + t * 8);
            gload_lds16(gA1 + k1, As[cur ^ 1] + 4096 + t * 8);
            gload_lds16(gB0 + k1, Bs[cur ^ 1] + t * 8);
            asm volatile("s_waitcnt vmcnt(3)" ::: "memory");
        } else {
            asm volatile("s_waitcnt vmcnt(0)" ::: "memory");
        }
        __builtin_amdgcn_s_barrier();
        __builtin_amdgcn_sched_barrier(0);
        bf16x8 af[4], bfr[4];
#pragma unroll
        for (int i = 0; i < 4; ++i)
            af[i] = *(const bf16x8*)(As[cur] + (ra + i * 16) * 32 + kos);
#pragma unroll
        for (int j = 0; j < 4; ++j)
            bfr[j] = *(const bf16x8*)(Bs[cur] + (rb + ((j & 1) * 16 + (j >> 1) * 32)) * 32 + kos);
        asm volatile("s_waitcnt lgkmcnt(0)" ::: "memory");
        __builtin_amdgcn_sched_barrier(0);
        __builtin_amdgcn_s_barrier();
#pragma unroll
        for (int i = 0; i < 4; ++i)
#pragma unroll
            for (int j = 0; j < 4; ++j)
                acc[i][j] = __builtin_amdgcn_mfma_f32_16x16x32_bf16(af[i], bfr[j], acc[i][j], 0, 0, 0);
        cur ^= 1;
    }

    const int rowb = m0 + wr * 64 + ((lane >> 4) * 4);
    u16* Cb = (u16*)Cv;
#pragma unroll
    for (int j = 0; j < 4; ++j) {
        int col = n0 + wc * 64 + ((j & 1) * 16 + (j >> 1) * 32) + (lane & 15);
        float bj = bias[col];
#pragma unroll
        for (int i = 0; i < 4; ++i) {
            int rw = rowb + i * 16;
#pragma unroll
            for (int r = 0; r < 4; ++r) {
                float v = acc[i][j][r] + bj;
                if (MODE == 2) v = fmaxf(v, 0.f);
                Cb[(size_t)(rw + r) * N + col] = f2bu(v);
            }
        }
    }
}

// ---------------- MFMA GEMM, 128x128 tile, 256 thr (ffn2) ---------------------
template<int MODE>
__global__ __launch_bounds__(256) void k_mgemm128(
        const u16* __restrict__ A, const u16* __restrict__ Bt,
        const float* __restrict__ bias, void* __restrict__ Cv,
        int K, int N, const void* __restrict__ extra,
        const float* __restrict__ extra2, int grow0, int gy) {
    __shared__ __align__(16) u16 As[2][128 * 32];
    __shared__ __align__(16) u16 Bs[2][128 * 32];
    const int swz = xcd_swz(blockIdx.x, gridDim.x);
    const int mb = swz / gy, nb = swz - mb * gy;
    const int m0 = mb * 128, n0 = nb * 128;
    const int t = threadIdx.x, lane = t & 63;
    const int wv = t >> 6, wr = wv >> 1, wc = wv & 1;

    const int kc = (t & 3) ^ ((t >> 3) & 3);
    const u16* gA0 = A  + (size_t)(m0 + (t >> 2)) * K + kc * 8;
    const u16* gA1 = A  + (size_t)(m0 + 64 + (t >> 2)) * K + kc * 8;
    const u16* gB0 = Bt + (size_t)(n0 + (t >> 2)) * K + kc * 8;
    const u16* gB1 = Bt + (size_t)(n0 + 64 + (t >> 2)) * K + kc * 8;

    f32x4 acc[4][4] = {};
    const int ra = wr * 64 + (lane & 15);
    const int rb = wc * 64 + (lane & 15);
    const int kos = (((lane >> 4) ^ (lane >> 1)) & 3) * 8;
    const int nIter = K >> 5;

    gload_lds16(gA0, As[0] + t * 8);
    gload_lds16(gA1, As[0] + 2048 + t * 8);
    gload_lds16(gB0, Bs[0] + t * 8);
    gload_lds16(gB1, Bs[0] + 2048 + t * 8);

    int cur = 0;
    for (int it = 0; it < nIter; ++it) {
        if (it + 1 < nIter) {
            const int k1 = (it + 1) << 5;
            gload_lds16(gA0 + k1, As[cur ^ 1] + t * 8);
            gload_lds16(gA1 + k1, As[cur ^ 1] + 2048 + t * 8);
            gload_lds16(gB0 + k1, Bs[cur ^ 1] + t * 8);
            gload_lds16(gB1 + k1, Bs[cur ^ 1] + 2048 + t * 8);
            asm volatile("s_waitcnt vmcnt(4)" ::: "memory");
        } else {
            asm volatile("s_waitcnt vmcnt(0)" ::: "memory");
        }
        __builtin_amdgcn_s_barrier();
        __builtin_amdgcn_sched_barrier(0);
        bf16x8 af[4], bfr[4];
#pragma unroll
        for (int i = 0; i < 4; ++i)
            af[i] = *(const bf16x8*)(As[cur] + (ra + i * 16) * 32 + kos);
#pragma unroll
        for (int j = 0; j < 4; ++j)
            bfr[j] = *(const bf16x8*)(Bs[cur] + (rb + j * 16) * 32 + kos);
        asm volatile("s_waitcnt lgkmcnt(0)" ::: "memory");
        __builtin_amdgcn_sched_barrier(0);
        __builtin_amdgcn_s_barrier();
#pragma unroll
        for (int i = 0; i < 4; ++i)
#pragma unroll
            for (int j = 0; j < 4; ++j)
                acc[i][j] = __builtin_amdgcn_mfma_f32_16x16x32_bf16(af[i], bfr[j], acc[i][j], 0, 0, 0);
        cur ^= 1;
    }

    const int colb = n0 + wc * 64 + (lane & 15);
    const int rowb = m0 + wr * 64 + ((lane >> 4) * 4);

    float* C = (float*)Cv;
    const u16* xr = (const u16*)extra;       // x1 bf16
#pragma unroll
    for (int j = 0; j < 4; ++j) {
        int col = colb + j * 16;
        float bj = bias[col], lj = extra2[col];
#pragma unroll
        for (int i = 0; i < 4; ++i) {
            int g  = grow0 + rowb + i * 16;   // 4-row pack never crosses batch
            int b  = g / HW, hw = g - b * HW;
            f32x4 o;
#pragma unroll
            for (int r = 0; r < 4; ++r)
                o[r] = bu2f(xr[(size_t)(g + r) * 256 + col]) + lj * (acc[i][j][r] + bj);
            *(f32x4*)(C + ((size_t)(b * 256 + col)) * HW + hw) = o;
        }
    }
}

// ---------------- fused attention + proj: one BLOCK per window ----------------
// R20 structure (Pl stride 68, PV rows clamped <=48, bf16x4 b64 loads) but
// WITHOUT the min-waves launch-bounds clamp: R20's (512,6) forced VGPR=40 ->
// massive scratch spills (FETCH+WRITE 339 MB, MfmaUtil 0.1%). Natural VGPR
// (~64-72) allows 8 waves/SIMD; occupancy is LDS-limited at 3 blocks/CU
// (53,760 x 3 = 161,280 <= 163,840).
__global__ __launch_bounds__(512) void k_attnproj(const u16* __restrict__ qkv,
        const u16* __restrict__ wpt, const float* __restrict__ pbias,
        u16* __restrict__ x1b) {
    __shared__ __align__(16) u16 U[8 * LWIN * PLS];   // 53,312 B
    const int wv = threadIdx.x >> 6, lane = threadIdx.x & 63;
    const int win = blockIdx.x, head = wv, wi = win & 63;
    const int rowbase = win * LWIN;
    const int g = lane >> 4, c = lane & 15, ko = g * 8;
    const u16* qb = qkv + (size_t)rowbase * 768 + head * 32;
    u16* pl = U + wv * (LWIN * PLS);

    bf16x8 vb[2][2];
#pragma unroll
    for (int j2 = 0; j2 < 2; ++j2) {
        int d = j2 * 16 + c;
#pragma unroll
        for (int h = 0; h < 2; ++h)
#pragma unroll
            for (int tt = 0; tt < 8; ++tt) {
                int k = h * 32 + ko + tt;
                u16 val = (k < LWIN) ? qb[(size_t)k * 768 + 512 + d] : (u16)0;
                vb[j2][h][tt] = __builtin_bit_cast(__bf16, val);
            }
    }

    bf16x8 qf[4], kf[4];
#pragma unroll
    for (int i = 0; i < 4; ++i) {
        int r0 = i * 16 + c; if (r0 > 48) r0 = 48;
        qf[i] = *(const bf16x8*)(qb + (size_t)r0 * 768 + ko);
        kf[i] = *(const bf16x8*)(qb + (size_t)r0 * 768 + 256 + ko);
    }
    f32x4 s[4][4] = {};
    __builtin_amdgcn_s_setprio(1);
#pragma unroll
    for (int i = 0; i < 4; ++i)
#pragma unroll
        for (int j = 0; j < 4; ++j)
            s[i][j] = __builtin_amdgcn_mfma_f32_16x16x32_bf16(qf[i], kf[j], s[i][j], 0, 0, 0);
    __builtin_amdgcn_s_setprio(0);

    const int wh7 = (wi >> 3) * 7, ww7 = (wi & 7) * 7;
    int idj[4]; bool jok[4];
#pragma unroll
    for (int j = 0; j < 4; ++j) {
        int col = j * 16 + c;
        jok[j] = col < LWIN;
        int p = jok[j] ? col : 48;
        idj[j] = region_of(wh7 + p / 7) * 3 + region_of(ww7 + p % 7);
    }
#pragma unroll
    for (int i = 0; i < 4; ++i) {
#pragma unroll
        for (int r = 0; r < 4; ++r) {
            int row = i * 16 + g * 4 + r;
            int p = row < LWIN ? row : 48;
            int idi = region_of(wh7 + p / 7) * 3 + region_of(ww7 + p % 7);
            float mx = -1e30f;
#pragma unroll
            for (int j = 0; j < 4; ++j) {
                float tv = jok[j] ? fmaf(s[i][j][r], 0.17677669529663687f,
                                         (idi == idj[j]) ? 0.f : -100.f)
                                  : -1e30f;
                s[i][j][r] = tv;
                mx = fmaxf(mx, tv);
            }
            for (int o = 8; o; o >>= 1) mx = fmaxf(mx, __shfl_xor(mx, o));
            float ps = 0.f;
#pragma unroll
            for (int j = 0; j < 4; ++j) {
                float e = __expf(s[i][j][r] - mx);
                s[i][j][r] = e; ps += e;
            }
            for (int o = 8; o; o >>= 1) ps += __shfl_xor(ps, o);
            float inv = 1.f / ps;
            if (row < LWIN) {
#pragma unroll
                for (int j = 0; j < 4; ++j)
                    pl[row * PLS + j * 16 + c] = f2bu(s[i][j][r] * inv);
            }
        }
    }
    // per-wave pl: compiler-inserted lgkmcnt orders write->read within the wave

    // --- O = P V: rows clamped <=48, fragments via two b64 bf16x4 loads ---
    f32x4 o[4][2] = {};
    __builtin_amdgcn_s_setprio(1);
#pragma unroll
    for (int i = 0; i < 4; ++i) {
        int rowA = i * 16 + c; if (rowA > 48) rowA = 48;
        const u16* pr = pl + rowA * PLS + ko;
        bf16x4 a0 = *(const bf16x4*)(pr);
        bf16x4 a1 = *(const bf16x4*)(pr + 4);
        bf16x4 b0 = *(const bf16x4*)(pr + 32);
        bf16x4 b1 = *(const bf16x4*)(pr + 36);
        bf16x8 pa0 = __builtin_shufflevector(a0, a1, 0, 1, 2, 3, 4, 5, 6, 7);
        bf16x8 pa1 = __builtin_shufflevector(b0, b1, 0, 1, 2, 3, 4, 5, 6, 7);
#pragma unroll
        for (int j2 = 0; j2 < 2; ++j2) {
            o[i][j2] = __builtin_amdgcn_mfma_f32_16x16x32_bf16(pa0, vb[j2][0], o[i][j2], 0, 0, 0);
            o[i][j2] = __builtin_amdgcn_mfma_f32_16x16x32_bf16(pa1, vb[j2][1], o[i][j2], 0, 0, 0);
        }
    }
    __builtin_amdgcn_s_setprio(0);

    __syncthreads();        // all waves done reading Pl -> U reusable as o_t

    // --- weight slice -> registers (no swizzle: regs have no banks) ---
    bf16x8 wreg[8][2];
#pragma unroll
    for (int it = 0; it < 8; ++it)
#pragma unroll
        for (int j2 = 0; j2 < 2; ++j2)
            wreg[it][j2] = *(const bf16x8*)(wpt +
                (size_t)(wv * 32 + j2 * 16 + c) * 256 + it * 32 + ko);

    // --- o_t = U (64 x 264: row stride 528 B -> 2-way banks, free) ---
    u16* o_t = U;
#pragma unroll
    for (int i = 0; i < 4; ++i)
#pragma unroll
        for (int r = 0; r < 4; ++r) {
            int row = i * 16 + g * 4 + r;
            if (row < LWIN) {
#pragma unroll
                for (int j2 = 0; j2 < 2; ++j2)
                    o_t[row * 264 + head * 32 + j2 * 16 + c] = f2bu(o[i][j2][r]);
            }
        }
    __syncthreads();        // o_t complete (rows >= 49 stale-garbage: discarded)

    // --- proj: 8 x {4 ds_read + 8 MFMA}, no barriers, weights in regs ---
    f32x4 acc2[4][2] = {};
#pragma unroll
    for (int it = 0; it < 8; ++it) {
        bf16x8 af[4];
#pragma unroll
        for (int i = 0; i < 4; ++i)
            af[i] = *(const bf16x8*)(o_t + (i * 16 + c) * 264 + it * 32 + ko);
        __builtin_amdgcn_s_setprio(1);
#pragma unroll
        for (int i = 0; i < 4; ++i)
#pragma unroll
            for (int j2 = 0; j2 < 2; ++j2)
                acc2[i][j2] = __builtin_amdgcn_mfma_f32_16x16x32_bf16(af[i], wreg[it][j2], acc2[i][j2], 0, 0, 0);
        __builtin_amdgcn_s_setprio(0);
    }

    // --- epilogue: scatter to x1b (proj_out) via row2tok, + bias ---
#pragma unroll
    for (int j2 = 0; j2 < 2; ++j2) {
        int col = wv * 32 + j2 * 16 + c;
        float bj = pbias[col];
#pragma unroll
        for (int i = 0; i < 4; ++i)
#pragma unroll
            for (int r = 0; r < 4; ++r) {
                int row = i * 16 + g * 4 + r;
                if (row < LWIN) {
                    int tok = row2tok(rowbase + row);
                    x1b[(size_t)tok * 256 + col] = f2bu(acc2[i][j2][r] + bj);
                }
            }
    }
}

extern "C" void kernel_launch(void* const* d_in, const int* in_sizes, int n_in,
                              void* d_out, int out_size, void* d_ws, size_t ws_size,
                              hipStream_t stream) {
    const float* x      = (const float*)d_in[0];
    const float* ln1_g  = (const float*)d_in[1];
    const float* ln1_b  = (const float*)d_in[2];
    const float* ln2_g  = (const float*)d_in[3];
    const float* ln2_b  = (const float*)d_in[4];
    const float* qkv_w  = (const float*)d_in[5];
    const float* qkv_b  = (const float*)d_in[6];
    const float* proj_w = (const float*)d_in[7];
    const float* proj_b = (const float*)d_in[8];
    const float* ffn_w1 = (const float*)d_in[9];
    const float* ffn_b1 = (const float*)d_in[10];
    const float* ffn_w2 = (const float*)d_in[11];
    const float* ffn_b2 = (const float*)d_in[12];
    const float* lscale = (const float*)d_in[13];

    // workspace: total 104,333,312 B (layout unchanged since R6)
    char* wsb = (char*)d_ws;
    u16* wqt  = (u16*)(wsb);
    u16* wpt  = (u16*)(wsb + 393216);
    u16* w1t  = (u16*)(wsb + 524288);
    u16* w2t  = (u16*)(wsb + 1048576);
    u16* P    = (u16*)(wsb + 1572864);
    char* Qb  = wsb + 27262976;
    u16* qkvb = (u16*)Qb;
    u16* x1b  = (u16*)Qb;
    u16* f1c  = (u16*)(Qb + 25690112);

    k_wconv_all<<<768, 256, 0, stream>>>(qkv_w, wqt, proj_w, wpt, ffn_w1, w1t, ffn_w2, w2t);

    k_ln1<<<16 * 98, 256, 0, stream>>>(x, ln1_g, ln1_b, P);
    // qkv: 196 m-blocks x 6 n-blocks, XCD-swizzled 1-D grid (1176 % 8 == 0)
    k_mgemm256<0><<<1176, 512, 0, stream>>>(P, wqt, qkv_b, qkvb, 256, 768, 6);
    // fused attention + proj -> proj_out (x1b, token-scattered bf16)
    k_attnproj<<<1024, 512, 0, stream>>>(qkvb, wpt, proj_b, x1b);
    // x1 = proj_out + transpose(x) (in-place), h2 = LN2(x1) -> P
    k_ln2t<<<16 * 98, 256, 0, stream>>>(x, x1b, ln2_g, ln2_b, P);
    for (int c = 0; c < 2; ++c) {
        // ffn1: 98 x 8 = 784 (784 % 8 == 0)
        k_mgemm256<2><<<784, 512, 0, stream>>>(P + (size_t)c * FCH * 256, w1t, ffn_b1,
                                               f1c, 256, 1024, 8);
        // ffn2: 196 x 2 = 392 (392 % 8 == 0)
        k_mgemm128<3><<<392, 256, 0, stream>>>(f1c, w2t, ffn_b2, d_out, 1024, 256,
                                               x1b, lscale, c * FCH, 2);
    }
}

// Round 22
// 237.027 us; speedup vs baseline: 1.3587x; 1.0196x over previous
//
#include <hip/hip_runtime.h>
#include <hip/hip_bf16.h>
#include <math.h>

typedef unsigned short u16;
typedef __bf16 bf16x8 __attribute__((ext_vector_type(8)));
typedef __bf16 bf16x4 __attribute__((ext_vector_type(4)));
typedef float  f32x4  __attribute__((ext_vector_type(4)));

#define DIMC 256
#define QSZ  56
#define WSZ  7
#define SSZ  3
#define LWIN 49
#define NWIN 64
#define HW   3136          // 56*56
#define NTOK 50176         // 16*3136
#define FFWD 1024
#define FCH  25088         // NTOK/2 ffn chunk rows
#define PLS  68            // Pl row stride u16: 136 B (b64-aligned); 8*49*68*2 = 53,312 B

__device__ __forceinline__ u16 f2bu(float f) {
    __hip_bfloat16 h = __float2bfloat16(f);
    return __builtin_bit_cast(u16, h);
}
__device__ __forceinline__ float bu2f(u16 u) {
    unsigned v = (unsigned)u << 16;
    return __builtin_bit_cast(float, v);
}
__device__ __forceinline__ void gload_lds16(const void* g, void* l) {
    __builtin_amdgcn_global_load_lds((const __attribute__((address_space(1))) void*)g,
                                     (__attribute__((address_space(3))) void*)l, 16, 0, 0);
}

// XCD-bijective swizzle (m204): nwg % 8 == 0 required.
__device__ __forceinline__ int xcd_swz(int flat, int nwg) {
    int q = nwg >> 3;
    return (flat & 7) * q + (flat >> 3);
}

__device__ __forceinline__ int region_of(int h) {
    return (h < 49) ? 0 : ((h < 53) ? 1 : 2);
}

// partitioned row m = ((b*64 + wi)*49 + p) -> flat token index (with roll by -3)
__device__ __forceinline__ int row2tok(int m) {
    int b  = m / (NWIN * LWIN);
    int r  = m - b * (NWIN * LWIN);
    int wi = r / LWIN;
    int p  = r - wi * LWIN;
    int wh = wi >> 3, ww = wi & 7;
    int ph = p / 7,   pw = p - ph * 7;
    int hr = wh * 7 + ph, wr = ww * 7 + pw;
    int hs = hr + SSZ; if (hs >= QSZ) hs -= QSZ;
    int ws2 = wr + SSZ; if (ws2 >= QSZ) ws2 -= QSZ;
    return b * HW + hs * QSZ + ws2;
}

// ---------------- merged weight transpose + bf16 convert (4 weights) ----------
__device__ __forceinline__ void wconv_body(const float* __restrict__ W,
        u16* __restrict__ Wt, int K, int N, int bx, int by, int t) {
    __shared__ float tile[32][33];
    int k0 = bx * 32, n0 = by * 32;
    int tx = t & 31, ty = t >> 5;
    for (int kk = ty; kk < 32; kk += 8)
        tile[kk][tx] = W[(size_t)(k0 + kk) * N + n0 + tx];
    __syncthreads();
    for (int nn = ty; nn < 32; nn += 8)
        Wt[(size_t)(n0 + nn) * K + k0 + tx] = f2bu(tile[tx][nn]);
}

__global__ __launch_bounds__(256) void k_wconv_all(
        const float* __restrict__ qkv_w, u16* __restrict__ wqt,
        const float* __restrict__ proj_w, u16* __restrict__ wpt,
        const float* __restrict__ ffn_w1, u16* __restrict__ w1t,
        const float* __restrict__ ffn_w2, u16* __restrict__ w2t) {
    int b = blockIdx.x, t = threadIdx.x;
    if (b < 192)        wconv_body(qkv_w, wqt, 256, 768, b & 7, b >> 3, t);
    else if (b < 256) { b -= 192; wconv_body(proj_w, wpt, 256, 256,  b & 7, b >> 3, t); }
    else if (b < 512) { b -= 256; wconv_body(ffn_w1, w1t, 256, 1024, b & 7, b >> 3, t); }
    else              { b -= 512; wconv_body(ffn_w2, w2t, 1024, 256, b & 31, b >> 5, t); }
}

// ---------------- K1: BCHW -> token-major transpose + LN1 -> bf16 -------------
__global__ __launch_bounds__(256) void k_ln1(const float* __restrict__ x,
        const float* __restrict__ g, const float* __restrict__ be,
        u16* __restrict__ hln) {
    __shared__ float tile[32][257];
    __shared__ float msh[32], rsh[32];
    int blk = blockIdx.x;            // 16 * 98
    int b   = blk / 98;
    int hw0 = (blk - b * 98) * 32;
    int t   = threadIdx.x;
    int tx  = t & 31, ty = t >> 5;
    for (int c = ty; c < 256; c += 8)
        tile[tx][c] = x[(size_t)(b * 256 + c) * HW + hw0 + tx];
    __syncthreads();
    int row = t >> 3, sub = t & 7;
    float s = 0.f, sq = 0.f;
    for (int c = sub * 32; c < sub * 32 + 32; ++c) {
        float v = tile[row][c]; s += v; sq += v * v;
    }
    for (int o = 4; o; o >>= 1) { s += __shfl_down(s, o, 8); sq += __shfl_down(sq, o, 8); }
    if (sub == 0) {
        float m   = s * (1.f / 256.f);
        float var = sq * (1.f / 256.f) - m * m;
        msh[row] = m; rsh[row] = rsqrtf(var + 1e-5f);
    }
    __syncthreads();
    float gg = g[t], bb = be[t];
    for (int r2 = 0; r2 < 32; ++r2) {
        float v = tile[r2][t];
        hln[(size_t)(b * HW + hw0 + r2) * 256 + t] = f2bu((v - msh[r2]) * rsh[r2] * gg + bb);
    }
}

// ---------------- LN2 + residual: x1 = proj_out + transpose(x); h2 = LN(x1) ---
__global__ __launch_bounds__(256) void k_ln2t(const float* __restrict__ x,
        u16* __restrict__ x1b, const float* __restrict__ g,
        const float* __restrict__ be, u16* __restrict__ h2) {
    __shared__ float tile[32][257];
    __shared__ float msh[32], rsh[32];
    int blk = blockIdx.x;            // 16 * 98
    int b   = blk / 98;
    int hw0 = (blk - b * 98) * 32;
    int t   = threadIdx.x;
    int tx  = t & 31, ty = t >> 5;
    for (int c = ty; c < 256; c += 8)
        tile[tx][c] = x[(size_t)(b * 256 + c) * HW + hw0 + tx];
    __syncthreads();
    size_t base = (size_t)b * HW + hw0;
    for (int r2 = 0; r2 < 32; ++r2) {
        float v = tile[r2][t] + bu2f(x1b[(base + r2) * 256 + t]);
        tile[r2][t] = v;
        x1b[(base + r2) * 256 + t] = f2bu(v);
    }
    __syncthreads();
    int row = t >> 3, sub = t & 7;
    float s = 0.f, sq = 0.f;
    for (int c = sub * 32; c < sub * 32 + 32; ++c) {
        float v = tile[row][c]; s += v; sq += v * v;
    }
    for (int o = 4; o; o >>= 1) { s += __shfl_down(s, o, 8); sq += __shfl_down(sq, o, 8); }
    if (sub == 0) {
        float m   = s * (1.f / 256.f);
        float var = sq * (1.f / 256.f) - m * m;
        msh[row] = m; rsh[row] = rsqrtf(var + 1e-5f);
    }
    __syncthreads();
    float gg = g[t], bb = be[t];
    for (int r2 = 0; r2 < 32; ++r2) {
        float v = tile[r2][t];
        h2[(base + r2) * 256 + t] = f2bu((v - msh[r2]) * rsh[r2] * gg + bb);
    }
}

// ---------------- MFMA GEMM, 256x128 tile, 512 thr (qkv / ffn1) ---------------
// R13-verified loop + T1 XCD grid (verified R17: -28 us).
template<int MODE>
__global__ __launch_bounds__(512) void k_mgemm256(
        const u16* __restrict__ A, const u16* __restrict__ Bt,
        const float* __restrict__ bias, void* __restrict__ Cv, int K, int N,
        int gy) {
    __shared__ __align__(16) u16 As[2][256 * 32];
    __shared__ __align__(16) u16 Bs[2][128 * 32];
    const int swz = xcd_swz(blockIdx.x, gridDim.x);
    const int mb = swz / gy, nb = swz - mb * gy;
    const int m0 = mb * 256, n0 = nb * 128;
    const int t = threadIdx.x, lane = t & 63;
    const int wv = t >> 6, wr = wv >> 1, wc = wv & 1;

    const int kc = (t & 3) ^ ((t >> 3) & 3);
    int ar0 = m0 + (t >> 2), ar1 = m0 + 128 + (t >> 2);
    if (MODE == 0) { ar0 = row2tok(ar0); ar1 = row2tok(ar1); }
    const u16* gA0 = A  + (size_t)ar0 * K + kc * 8;
    const u16* gA1 = A  + (size_t)ar1 * K + kc * 8;
    const u16* gB0 = Bt + (size_t)(n0 + (t >> 2)) * K + kc * 8;

    f32x4 acc[4][4] = {};
    const int ra = wr * 64 + (lane & 15);
    const int rb = wc * 64 + (lane & 15);
    const int kos = (((lane >> 4) ^ (lane >> 1)) & 3) * 8;
    const int nIter = K >> 5;

    gload_lds16(gA0, As[0] + t * 8);
    gload_lds16(gA1, As[0] + 4096 + t * 8);
    gload_lds16(gB0, Bs[0] + t * 8);

    int cur = 0;
    for (int it = 0; it < nIter; ++it) {
        if (it + 1 < nIter) {
            const int k1 = (it + 1) << 5;
            gload_lds16(gA0 + k1, As[cur ^ 1] + t * 8);
            gload_lds16(gA1 + k1, As[cur ^ 1] + 4096 + t * 8);
            gload_lds16(gB0 + k1, Bs[cur ^ 1] + t * 8);
            asm volatile("s_waitcnt vmcnt(3)" ::: "memory");
        } else {
            asm volatile("s_waitcnt vmcnt(0)" ::: "memory");
        }
        __builtin_amdgcn_s_barrier();
        __builtin_amdgcn_sched_barrier(0);
        bf16x8 af[4], bfr[4];
#pragma unroll
        for (int i = 0; i < 4; ++i)
            af[i] = *(const bf16x8*)(As[cur] + (ra + i * 16) * 32 + kos);
#pragma unroll
        for (int j = 0; j < 4; ++j)
            bfr[j] = *(const bf16x8*)(Bs[cur] + (rb + ((j & 1) * 16 + (j >> 1) * 32)) * 32 + kos);
        asm volatile("s_waitcnt lgkmcnt(0)" ::: "memory");
        __builtin_amdgcn_sched_barrier(0);
        __builtin_amdgcn_s_barrier();
#pragma unroll
        for (int i = 0; i < 4; ++i)
#pragma unroll
            for (int j = 0; j < 4; ++j)
                acc[i][j] = __builtin_amdgcn_mfma_f32_16x16x32_bf16(af[i], bfr[j], acc[i][j], 0, 0, 0);
        cur ^= 1;
    }

    const int rowb = m0 + wr * 64 + ((lane >> 4) * 4);
    u16* Cb = (u16*)Cv;
#pragma unroll
    for (int j = 0; j < 4; ++j) {
        int col = n0 + wc * 64 + ((j & 1) * 16 + (j >> 1) * 32) + (lane & 15);
        float bj = bias[col];
#pragma unroll
        for (int i = 0; i < 4; ++i) {
            int rw = rowb + i * 16;
#pragma unroll
            for (int r = 0; r < 4; ++r) {
                float v = acc[i][j][r] + bj;
                if (MODE == 2) v = fmaxf(v, 0.f);
                Cb[(size_t)(rw + r) * N + col] = f2bu(v);
            }
        }
    }
}

// ---------------- MFMA GEMM, 128x128 tile, 256 thr (ffn2) ---------------------
template<int MODE>
__global__ __launch_bounds__(256) void k_mgemm128(
        const u16* __restrict__ A, const u16* __restrict__ Bt,
        const float* __restrict__ bias, void* __restrict__ Cv,
        int K, int N, const void* __restrict__ extra,
        const float* __restrict__ extra2, int grow0, int gy) {
    __shared__ __align__(16) u16 As[2][128 * 32];
    __shared__ __align__(16) u16 Bs[2][128 * 32];
    const int swz = xcd_swz(blockIdx.x, gridDim.x);
    const int mb = swz / gy, nb = swz - mb * gy;
    const int m0 = mb * 128, n0 = nb * 128;
    const int t = threadIdx.x, lane = t & 63;
    const int wv = t >> 6, wr = wv >> 1, wc = wv & 1;

    const int kc = (t & 3) ^ ((t >> 3) & 3);
    const u16* gA0 = A  + (size_t)(m0 + (t >> 2)) * K + kc * 8;
    const u16* gA1 = A  + (size_t)(m0 + 64 + (t >> 2)) * K + kc * 8;
    const u16* gB0 = Bt + (size_t)(n0 + (t >> 2)) * K + kc * 8;
    const u16* gB1 = Bt + (size_t)(n0 + 64 + (t >> 2)) * K + kc * 8;

    f32x4 acc[4][4] = {};
    const int ra = wr * 64 + (lane & 15);
    const int rb = wc * 64 + (lane & 15);
    const int kos = (((lane >> 4) ^ (lane >> 1)) & 3) * 8;
    const int nIter = K >> 5;

    gload_lds16(gA0, As[0] + t * 8);
    gload_lds16(gA1, As[0] + 2048 + t * 8);
    gload_lds16(gB0, Bs[0] + t * 8);
    gload_lds16(gB1, Bs[0] + 2048 + t * 8);

    int cur = 0;
    for (int it = 0; it < nIter; ++it) {
        if (it + 1 < nIter) {
            const int k1 = (it + 1) << 5;
            gload_lds16(gA0 + k1, As[cur ^ 1] + t * 8);
            gload_lds16(gA1 + k1, As[cur ^ 1] + 2048 + t * 8);
            gload_lds16(gB0 + k1, Bs[cur ^ 1] + t * 8);
            gload_lds16(gB1 + k1, Bs[cur ^ 1] + 2048 + t * 8);
            asm volatile("s_waitcnt vmcnt(4)" ::: "memory");
        } else {
            asm volatile("s_waitcnt vmcnt(0)" ::: "memory");
        }
        __builtin_amdgcn_s_barrier();
        __builtin_amdgcn_sched_barrier(0);
        bf16x8 af[4], bfr[4];
#pragma unroll
        for (int i = 0; i < 4; ++i)
            af[i] = *(const bf16x8*)(As[cur] + (ra + i * 16) * 32 + kos);
#pragma unroll
        for (int j = 0; j < 4; ++j)
            bfr[j] = *(const bf16x8*)(Bs[cur] + (rb + j * 16) * 32 + kos);
        asm volatile("s_waitcnt lgkmcnt(0)" ::: "memory");
        __builtin_amdgcn_sched_barrier(0);
        __builtin_amdgcn_s_barrier();
#pragma unroll
        for (int i = 0; i < 4; ++i)
#pragma unroll
            for (int j = 0; j < 4; ++j)
                acc[i][j] = __builtin_amdgcn_mfma_f32_16x16x32_bf16(af[i], bfr[j], acc[i][j], 0, 0, 0);
        cur ^= 1;
    }

    const int colb = n0 + wc * 64 + (lane & 15);
    const int rowb = m0 + wr * 64 + ((lane >> 4) * 4);

    float* C = (float*)Cv;
    const u16* xr = (const u16*)extra;       // x1 bf16
#pragma unroll
    for (int j = 0; j < 4; ++j) {
        int col = colb + j * 16;
        float bj = bias[col], lj = extra2[col];
#pragma unroll
        for (int i = 0; i < 4; ++i) {
            int g  = grow0 + rowb + i * 16;   // 4-row pack never crosses batch
            int b  = g / HW, hw = g - b * HW;
            f32x4 o;
#pragma unroll
            for (int r = 0; r < 4; ++r)
                o[r] = bu2f(xr[(size_t)(g + r) * 256 + col]) + lj * (acc[i][j][r] + bj);
            *(f32x4*)(C + ((size_t)(b * 256 + col)) * HW + hw) = o;
        }
    }
}

// ---------------- fused attention + proj: one BLOCK per window ----------------
// R21 structure with SWAPPED QK^T (T12 core idea): s[i][j] = mfma(kf[j], qf[i])
// puts S[qrow = i*16+c][kcol = j*16+g*4+r] in-lane -> softmax row-reduce is an
// in-lane chain over 16 regs + TWO shfl_xor (16,32) per qrow (vs 8 per slice
// before: 128 -> 8 shuffles/lane). Pl contents identical to R21 (verified PV /
// proj / epilogue untouched); Pl writes packed as ushort4 (136-B row pitch is
// 8-B aligned).
__global__ __launch_bounds__(512) void k_attnproj(const u16* __restrict__ qkv,
        const u16* __restrict__ wpt, const float* __restrict__ pbias,
        u16* __restrict__ x1b) {
    __shared__ __align__(16) u16 U[8 * LWIN * PLS];   // 53,312 B
    const int wv = threadIdx.x >> 6, lane = threadIdx.x & 63;
    const int win = blockIdx.x, head = wv, wi = win & 63;
    const int rowbase = win * LWIN;
    const int g = lane >> 4, c = lane & 15, ko = g * 8;
    const u16* qb = qkv + (size_t)rowbase * 768 + head * 32;
    u16* pl = U + wv * (LWIN * PLS);

    bf16x8 vb[2][2];
#pragma unroll
    for (int j2 = 0; j2 < 2; ++j2) {
        int d = j2 * 16 + c;
#pragma unroll
        for (int h = 0; h < 2; ++h)
#pragma unroll
            for (int tt = 0; tt < 8; ++tt) {
                int k = h * 32 + ko + tt;
                u16 val = (k < LWIN) ? qb[(size_t)k * 768 + 512 + d] : (u16)0;
                vb[j2][h][tt] = __builtin_bit_cast(__bf16, val);
            }
    }

    bf16x8 qf[4], kf[4];
#pragma unroll
    for (int i = 0; i < 4; ++i) {
        int r0 = i * 16 + c; if (r0 > 48) r0 = 48;   // clamp: garbage rows unused
        qf[i] = *(const bf16x8*)(qb + (size_t)r0 * 768 + ko);
        kf[i] = *(const bf16x8*)(qb + (size_t)r0 * 768 + 256 + ko);
    }
    // --- S^T fragments: s[i][j] = K_j^T Q_i -> lane holds qrow=i*16+c,
    //     kcol = j*16 + g*4 + r  (m89 C/D layout with A=kf, B=qf) ---
    f32x4 s[4][4] = {};
    __builtin_amdgcn_s_setprio(1);
#pragma unroll
    for (int i = 0; i < 4; ++i)
#pragma unroll
        for (int j = 0; j < 4; ++j)
            s[i][j] = __builtin_amdgcn_mfma_f32_16x16x32_bf16(kf[j], qf[i], s[i][j], 0, 0, 0);
    __builtin_amdgcn_s_setprio(0);

    // --- masked softmax, lane-local rows ---
    const int wh7 = (wi >> 3) * 7, ww7 = (wi & 7) * 7;
    int idjn[4][4]; bool jokn[4][4];
#pragma unroll
    for (int j = 0; j < 4; ++j)
#pragma unroll
        for (int r = 0; r < 4; ++r) {
            int kcol = j * 16 + g * 4 + r;
            jokn[j][r] = kcol < LWIN;
            int p = jokn[j][r] ? kcol : 48;
            idjn[j][r] = region_of(wh7 + p / 7) * 3 + region_of(ww7 + p % 7);
        }
#pragma unroll
    for (int i = 0; i < 4; ++i) {
        int qrow = i * 16 + c;
        int p = qrow < LWIN ? qrow : 48;
        int idi = region_of(wh7 + p / 7) * 3 + region_of(ww7 + p % 7);
        float mx = -1e30f;
#pragma unroll
        for (int j = 0; j < 4; ++j)
#pragma unroll
            for (int r = 0; r < 4; ++r) {
                float tv = jokn[j][r] ? fmaf(s[i][j][r], 0.17677669529663687f,
                                             (idi == idjn[j][r]) ? 0.f : -100.f)
                                      : -1e30f;
                s[i][j][r] = tv;
                mx = fmaxf(mx, tv);
            }
        mx = fmaxf(mx, __shfl_xor(mx, 16));
        mx = fmaxf(mx, __shfl_xor(mx, 32));
        float ps = 0.f;
#pragma unroll
        for (int j = 0; j < 4; ++j)
#pragma unroll
            for (int r = 0; r < 4; ++r) {
                float e = __expf(s[i][j][r] - mx);
                s[i][j][r] = e; ps += e;
            }
        ps += __shfl_xor(ps, 16);
        ps += __shfl_xor(ps, 32);
        float inv = 1.f / ps;
        if (qrow < LWIN) {
#pragma unroll
            for (int j = 0; j < 4; ++j) {
                ushort4 st{f2bu(s[i][j][0] * inv), f2bu(s[i][j][1] * inv),
                           f2bu(s[i][j][2] * inv), f2bu(s[i][j][3] * inv)};
                *(ushort4*)(pl + qrow * PLS + j * 16 + g * 4) = st;
            }
        }
    }
    // per-wave pl: compiler-inserted lgkmcnt orders write->read within the wave

    // --- O = P V: rows clamped <=48, fragments via two b64 bf16x4 loads ---
    f32x4 o[4][2] = {};
    __builtin_amdgcn_s_setprio(1);
#pragma unroll
    for (int i = 0; i < 4; ++i) {
        int rowA = i * 16 + c; if (rowA > 48) rowA = 48;
        const u16* pr = pl + rowA * PLS + ko;
        bf16x4 a0 = *(const bf16x4*)(pr);
        bf16x4 a1 = *(const bf16x4*)(pr + 4);
        bf16x4 b0 = *(const bf16x4*)(pr + 32);
        bf16x4 b1 = *(const bf16x4*)(pr + 36);
        bf16x8 pa0 = __builtin_shufflevector(a0, a1, 0, 1, 2, 3, 4, 5, 6, 7);
        bf16x8 pa1 = __builtin_shufflevector(b0, b1, 0, 1, 2, 3, 4, 5, 6, 7);
#pragma unroll
        for (int j2 = 0; j2 < 2; ++j2) {
            o[i][j2] = __builtin_amdgcn_mfma_f32_16x16x32_bf16(pa0, vb[j2][0], o[i][j2], 0, 0, 0);
            o[i][j2] = __builtin_amdgcn_mfma_f32_16x16x32_bf16(pa1, vb[j2][1], o[i][j2], 0, 0, 0);
        }
    }
    __builtin_amdgcn_s_setprio(0);

    __syncthreads();        // all waves done reading Pl -> U reusable as o_t

    // --- weight slice -> registers (no swizzle: regs have no banks) ---
    bf16x8 wreg[8][2];
#pragma unroll
    for (int it = 0; it < 8; ++it)
#pragma unroll
        for (int j2 = 0; j2 < 2; ++j2)
            wreg[it][j2] = *(const bf16x8*)(wpt +
                (size_t)(wv * 32 + j2 * 16 + c) * 256 + it * 32 + ko);

    // --- o_t = U (64 x 264: row stride 528 B -> 2-way banks, free) ---
    u16* o_t = U;
#pragma unroll
    for (int i = 0; i < 4; ++i)
#pragma unroll
        for (int r = 0; r < 4; ++r) {
            int row = i * 16 + g * 4 + r;
            if (row < LWIN) {
#pragma unroll
                for (int j2 = 0; j2 < 2; ++j2)
                    o_t[row * 264 + head * 32 + j2 * 16 + c] = f2bu(o[i][j2][r]);
            }
        }
    __syncthreads();        // o_t complete (rows >= 49 stale-garbage: discarded)

    // --- proj: 8 x {4 ds_read + 8 MFMA}, no barriers, weights in regs ---
    f32x4 acc2[4][2] = {};
#pragma unroll
    for (int it = 0; it < 8; ++it) {
        bf16x8 af[4];
#pragma unroll
        for (int i = 0; i < 4; ++i)
            af[i] = *(const bf16x8*)(o_t + (i * 16 + c) * 264 + it * 32 + ko);
        __builtin_amdgcn_s_setprio(1);
#pragma unroll
        for (int i = 0; i < 4; ++i)
#pragma unroll
            for (int j2 = 0; j2 < 2; ++j2)
                acc2[i][j2] = __builtin_amdgcn_mfma_f32_16x16x32_bf16(af[i], wreg[it][j2], acc2[i][j2], 0, 0, 0);
        __builtin_amdgcn_s_setprio(0);
    }

    // --- epilogue: scatter to x1b (proj_out) via row2tok, + bias ---
#pragma unroll
    for (int j2 = 0; j2 < 2; ++j2) {
        int col = wv * 32 + j2 * 16 + c;
        float bj = pbias[col];
#pragma unroll
        for (int i = 0; i < 4; ++i)
#pragma unroll
            for (int r = 0; r < 4; ++r) {
                int row = i * 16 + g * 4 + r;
                if (row < LWIN) {
                    int tok = row2tok(rowbase + row);
                    x1b[(size_t)tok * 256 + col] = f2bu(acc2[i][j2][r] + bj);
                }
            }
    }
}

extern "C" void kernel_launch(void* const* d_in, const int* in_sizes, int n_in,
                              void* d_out, int out_size, void* d_ws, size_t ws_size,
                              hipStream_t stream) {
    const float* x      = (const float*)d_in[0];
    const float* ln1_g  = (const float*)d_in[1];
    const float* ln1_b  = (const float*)d_in[2];
    const float* ln2_g  = (const float*)d_in[3];
    const float* ln2_b  = (const float*)d_in[4];
    const float* qkv_w  = (const float*)d_in[5];
    const float* qkv_b  = (const float*)d_in[6];
    const float* proj_w = (const float*)d_in[7];
    const float* proj_b = (const float*)d_in[8];
    const float* ffn_w1 = (const float*)d_in[9];
    const float* ffn_b1 = (const float*)d_in[10];
    const float* ffn_w2 = (const float*)d_in[11];
    const float* ffn_b2 = (const float*)d_in[12];
    const float* lscale = (const float*)d_in[13];

    // workspace: total 104,333,312 B (layout unchanged since R6)
    char* wsb = (char*)d_ws;
    u16* wqt  = (u16*)(wsb);
    u16* wpt  = (u16*)(wsb + 393216);
    u16* w1t  = (u16*)(wsb + 524288);
    u16* w2t  = (u16*)(wsb + 1048576);
    u16* P    = (u16*)(wsb + 1572864);
    char* Qb  = wsb + 27262976;
    u16* qkvb = (u16*)Qb;
    u16* x1b  = (u16*)Qb;
    u16* f1c  = (u16*)(Qb + 25690112);

    k_wconv_all<<<768, 256, 0, stream>>>(qkv_w, wqt, proj_w, wpt, ffn_w1, w1t, ffn_w2, w2t);

    k_ln1<<<16 * 98, 256, 0, stream>>>(x, ln1_g, ln1_b, P);
    // qkv: 196 m-blocks x 6 n-blocks, XCD-swizzled 1-D grid (1176 % 8 == 0)
    k_mgemm256<0><<<1176, 512, 0, stream>>>(P, wqt, qkv_b, qkvb, 256, 768, 6);
    // fused attention + proj -> proj_out (x1b, token-scattered bf16)
    k_attnproj<<<1024, 512, 0, stream>>>(qkvb, wpt, proj_b, x1b);
    // x1 = proj_out + transpose(x) (in-place), h2 = LN2(x1) -> P
    k_ln2t<<<16 * 98, 256, 0, stream>>>(x, x1b, ln2_g, ln2_b, P);
    for (int c = 0; c < 2; ++c) {
        // ffn1: 98 x 8 = 784 (784 % 8 == 0)
        k_mgemm256<2><<<784, 512, 0, stream>>>(P + (size_t)c * FCH * 256, w1t, ffn_b1,
                                               f1c, 256, 1024, 8);
        // ffn2: 196 x 2 = 392 (392 % 8 == 0)
        k_mgemm128<3><<<392, 256, 0, stream>>>(f1c, w2t, ffn_b2, d_out, 1024, 256,
                                               x1b, lscale, c * FCH, 2);
    }
}

// Round 23
// 230.665 us; speedup vs baseline: 1.3962x; 1.0276x over previous
//
#include <hip/hip_runtime.h>
#include <hip/hip_bf16.h>
#include <math.h>

typedef unsigned short u16;
typedef __bf16 bf16x8 __attribute__((ext_vector_type(8)));
typedef __bf16 bf16x4 __attribute__((ext_vector_type(4)));
typedef float  f32x4  __attribute__((ext_vector_type(4)));

#define DIMC 256
#define QSZ  56
#define WSZ  7
#define SSZ  3
#define LWIN 49
#define NWIN 64
#define HW   3136          // 56*56
#define NTOK 50176         // 16*3136
#define FFWD 1024
#define FCH  25088         // NTOK/2 ffn chunk rows
#define PLS  68            // Pl row stride u16: 136 B (b64-aligned); 8*49*68*2 = 53,312 B

__device__ __forceinline__ u16 f2bu(float f) {
    __hip_bfloat16 h = __float2bfloat16(f);
    return __builtin_bit_cast(u16, h);
}
__device__ __forceinline__ float bu2f(u16 u) {
    unsigned v = (unsigned)u << 16;
    return __builtin_bit_cast(float, v);
}
__device__ __forceinline__ void gload_lds16(const void* g, void* l) {
    __builtin_amdgcn_global_load_lds((const __attribute__((address_space(1))) void*)g,
                                     (__attribute__((address_space(3))) void*)l, 16, 0, 0);
}

// XCD-bijective swizzle (m204): nwg % 8 == 0 required.
__device__ __forceinline__ int xcd_swz(int flat, int nwg) {
    int q = nwg >> 3;
    return (flat & 7) * q + (flat >> 3);
}

__device__ __forceinline__ int region_of(int h) {
    return (h < 49) ? 0 : ((h < 53) ? 1 : 2);
}

// partitioned row m = ((b*64 + wi)*49 + p) -> flat token index (with roll by -3)
__device__ __forceinline__ int row2tok(int m) {
    int b  = m / (NWIN * LWIN);
    int r  = m - b * (NWIN * LWIN);
    int wi = r / LWIN;
    int p  = r - wi * LWIN;
    int wh = wi >> 3, ww = wi & 7;
    int ph = p / 7,   pw = p - ph * 7;
    int hr = wh * 7 + ph, wr = ww * 7 + pw;
    int hs = hr + SSZ; if (hs >= QSZ) hs -= QSZ;
    int ws2 = wr + SSZ; if (ws2 >= QSZ) ws2 -= QSZ;
    return b * HW + hs * QSZ + ws2;
}

// ---------------- merged weight transpose + bf16 convert (4 weights) ----------
__device__ __forceinline__ void wconv_body(const float* __restrict__ W,
        u16* __restrict__ Wt, int K, int N, int bx, int by, int t) {
    __shared__ float tile[32][33];
    int k0 = bx * 32, n0 = by * 32;
    int tx = t & 31, ty = t >> 5;
    for (int kk = ty; kk < 32; kk += 8)
        tile[kk][tx] = W[(size_t)(k0 + kk) * N + n0 + tx];
    __syncthreads();
    for (int nn = ty; nn < 32; nn += 8)
        Wt[(size_t)(n0 + nn) * K + k0 + tx] = f2bu(tile[tx][nn]);
}

__global__ __launch_bounds__(256) void k_wconv_all(
        const float* __restrict__ qkv_w, u16* __restrict__ wqt,
        const float* __restrict__ proj_w, u16* __restrict__ wpt,
        const float* __restrict__ ffn_w1, u16* __restrict__ w1t,
        const float* __restrict__ ffn_w2, u16* __restrict__ w2t) {
    int b = blockIdx.x, t = threadIdx.x;
    if (b < 192)        wconv_body(qkv_w, wqt, 256, 768, b & 7, b >> 3, t);
    else if (b < 256) { b -= 192; wconv_body(proj_w, wpt, 256, 256,  b & 7, b >> 3, t); }
    else if (b < 512) { b -= 256; wconv_body(ffn_w1, w1t, 256, 1024, b & 7, b >> 3, t); }
    else              { b -= 512; wconv_body(ffn_w2, w2t, 1024, 256, b & 31, b >> 5, t); }
}

// ---------------- K1: BCHW -> token-major transpose + LN1 -> bf16 -------------
// Reduce loop reads ROTATED per sub-lane (cc = sub*32 + ((i+4*sub)&31)):
// the straight order had all 8 subs of a row on one bank (257%32==1,
// sub*32%32==0) -> 8-way conflict every step; rotation spreads to ~2-way.
__global__ __launch_bounds__(256) void k_ln1(const float* __restrict__ x,
        const float* __restrict__ g, const float* __restrict__ be,
        u16* __restrict__ hln) {
    __shared__ float tile[32][257];
    __shared__ float msh[32], rsh[32];
    int blk = blockIdx.x;            // 16 * 98
    int b   = blk / 98;
    int hw0 = (blk - b * 98) * 32;
    int t   = threadIdx.x;
    int tx  = t & 31, ty = t >> 5;
    for (int c = ty; c < 256; c += 8)
        tile[tx][c] = x[(size_t)(b * 256 + c) * HW + hw0 + tx];
    __syncthreads();
    int row = t >> 3, sub = t & 7;
    float s = 0.f, sq = 0.f;
    for (int i = 0; i < 32; ++i) {
        int cc = sub * 32 + ((i + sub * 4) & 31);
        float v = tile[row][cc]; s += v; sq += v * v;
    }
    for (int o = 4; o; o >>= 1) { s += __shfl_down(s, o, 8); sq += __shfl_down(sq, o, 8); }
    if (sub == 0) {
        float m   = s * (1.f / 256.f);
        float var = sq * (1.f / 256.f) - m * m;
        msh[row] = m; rsh[row] = rsqrtf(var + 1e-5f);
    }
    __syncthreads();
    float gg = g[t], bb = be[t];
    for (int r2 = 0; r2 < 32; ++r2) {
        float v = tile[r2][t];
        hln[(size_t)(b * HW + hw0 + r2) * 256 + t] = f2bu((v - msh[r2]) * rsh[r2] * gg + bb);
    }
}

// ---------------- LN2 + residual: x1 = proj_out + transpose(x); h2 = LN(x1) ---
// Same rotated reduce as k_ln1.
__global__ __launch_bounds__(256) void k_ln2t(const float* __restrict__ x,
        u16* __restrict__ x1b, const float* __restrict__ g,
        const float* __restrict__ be, u16* __restrict__ h2) {
    __shared__ float tile[32][257];
    __shared__ float msh[32], rsh[32];
    int blk = blockIdx.x;            // 16 * 98
    int b   = blk / 98;
    int hw0 = (blk - b * 98) * 32;
    int t   = threadIdx.x;
    int tx  = t & 31, ty = t >> 5;
    for (int c = ty; c < 256; c += 8)
        tile[tx][c] = x[(size_t)(b * 256 + c) * HW + hw0 + tx];
    __syncthreads();
    size_t base = (size_t)b * HW + hw0;
    for (int r2 = 0; r2 < 32; ++r2) {
        float v = tile[r2][t] + bu2f(x1b[(base + r2) * 256 + t]);
        tile[r2][t] = v;
        x1b[(base + r2) * 256 + t] = f2bu(v);
    }
    __syncthreads();
    int row = t >> 3, sub = t & 7;
    float s = 0.f, sq = 0.f;
    for (int i = 0; i < 32; ++i) {
        int cc = sub * 32 + ((i + sub * 4) & 31);
        float v = tile[row][cc]; s += v; sq += v * v;
    }
    for (int o = 4; o; o >>= 1) { s += __shfl_down(s, o, 8); sq += __shfl_down(sq, o, 8); }
    if (sub == 0) {
        float m   = s * (1.f / 256.f);
        float var = sq * (1.f / 256.f) - m * m;
        msh[row] = m; rsh[row] = rsqrtf(var + 1e-5f);
    }
    __syncthreads();
    float gg = g[t], bb = be[t];
    for (int r2 = 0; r2 < 32; ++r2) {
        float v = tile[r2][t];
        h2[(base + r2) * 256 + t] = f2bu((v - msh[r2]) * rsh[r2] * gg + bb);
    }
}

// ---------------- MFMA GEMM, 256x128 tile, 512 thr (qkv / ffn1) ---------------
// R13-verified loop + T1 XCD grid (verified R17: -28 us).
template<int MODE>
__global__ __launch_bounds__(512) void k_mgemm256(
        const u16* __restrict__ A, const u16* __restrict__ Bt,
        const float* __restrict__ bias, void* __restrict__ Cv, int K, int N,
        int gy) {
    __shared__ __align__(16) u16 As[2][256 * 32];
    __shared__ __align__(16) u16 Bs[2][128 * 32];
    const int swz = xcd_swz(blockIdx.x, gridDim.x);
    const int mb = swz / gy, nb = swz - mb * gy;
    const int m0 = mb * 256, n0 = nb * 128;
    const int t = threadIdx.x, lane = t & 63;
    const int wv = t >> 6, wr = wv >> 1, wc = wv & 1;

    const int kc = (t & 3) ^ ((t >> 3) & 3);
    int ar0 = m0 + (t >> 2), ar1 = m0 + 128 + (t >> 2);
    if (MODE == 0) { ar0 = row2tok(ar0); ar1 = row2tok(ar1); }
    const u16* gA0 = A  + (size_t)ar0 * K + kc * 8;
    const u16* gA1 = A  + (size_t)ar1 * K + kc * 8;
    const u16* gB0 = Bt + (size_t)(n0 + (t >> 2)) * K + kc * 8;

    f32x4 acc[4][4] = {};
    const int ra = wr * 64 + (lane & 15);
    const int rb = wc * 64 + (lane & 15);
    const int kos = (((lane >> 4) ^ (lane >> 1)) & 3) * 8;
    const int nIter = K >> 5;

    gload_lds16(gA0, As[0] + t * 8);
    gload_lds16(gA1, As[0] + 4096 + t * 8);
    gload_lds16(gB0, Bs[0] + t * 8);

    int cur = 0;
    for (int it = 0; it < nIter; ++it) {
        if (it + 1 < nIter) {
            const int k1 = (it + 1) << 5;
            gload_lds16(gA0 + k1, As[cur ^ 1] + t * 8);
            gload_lds16(gA1 + k1, As[cur ^ 1] + 4096 + t * 8);
            gload_lds16(gB0 + k1, Bs[cur ^ 1] + t * 8);
            asm volatile("s_waitcnt vmcnt(3)" ::: "memory");
        } else {
            asm volatile("s_waitcnt vmcnt(0)" ::: "memory");
        }
        __builtin_amdgcn_s_barrier();
        __builtin_amdgcn_sched_barrier(0);
        bf16x8 af[4], bfr[4];
#pragma unroll
        for (int i = 0; i < 4; ++i)
            af[i] = *(const bf16x8*)(As[cur] + (ra + i * 16) * 32 + kos);
#pragma unroll
        for (int j = 0; j < 4; ++j)
            bfr[j] = *(const bf16x8*)(Bs[cur] + (rb + ((j & 1) * 16 + (j >> 1) * 32)) * 32 + kos);
        asm volatile("s_waitcnt lgkmcnt(0)" ::: "memory");
        __builtin_amdgcn_sched_barrier(0);
        __builtin_amdgcn_s_barrier();
#pragma unroll
        for (int i = 0; i < 4; ++i)
#pragma unroll
            for (int j = 0; j < 4; ++j)
                acc[i][j] = __builtin_amdgcn_mfma_f32_16x16x32_bf16(af[i], bfr[j], acc[i][j], 0, 0, 0);
        cur ^= 1;
    }

    const int rowb = m0 + wr * 64 + ((lane >> 4) * 4);
    u16* Cb = (u16*)Cv;
#pragma unroll
    for (int j = 0; j < 4; ++j) {
        int col = n0 + wc * 64 + ((j & 1) * 16 + (j >> 1) * 32) + (lane & 15);
        float bj = bias[col];
#pragma unroll
        for (int i = 0; i < 4; ++i) {
            int rw = rowb + i * 16;
#pragma unroll
            for (int r = 0; r < 4; ++r) {
                float v = acc[i][j][r] + bj;
                if (MODE == 2) v = fmaxf(v, 0.f);
                Cb[(size_t)(rw + r) * N + col] = f2bu(v);
            }
        }
    }
}

// ---------------- MFMA GEMM, 128x128 tile, 256 thr (ffn2) ---------------------
template<int MODE>
__global__ __launch_bounds__(256) void k_mgemm128(
        const u16* __restrict__ A, const u16* __restrict__ Bt,
        const float* __restrict__ bias, void* __restrict__ Cv,
        int K, int N, const void* __restrict__ extra,
        const float* __restrict__ extra2, int grow0, int gy) {
    __shared__ __align__(16) u16 As[2][128 * 32];
    __shared__ __align__(16) u16 Bs[2][128 * 32];
    const int swz = xcd_swz(blockIdx.x, gridDim.x);
    const int mb = swz / gy, nb = swz - mb * gy;
    const int m0 = mb * 128, n0 = nb * 128;
    const int t = threadIdx.x, lane = t & 63;
    const int wv = t >> 6, wr = wv >> 1, wc = wv & 1;

    const int kc = (t & 3) ^ ((t >> 3) & 3);
    const u16* gA0 = A  + (size_t)(m0 + (t >> 2)) * K + kc * 8;
    const u16* gA1 = A  + (size_t)(m0 + 64 + (t >> 2)) * K + kc * 8;
    const u16* gB0 = Bt + (size_t)(n0 + (t >> 2)) * K + kc * 8;
    const u16* gB1 = Bt + (size_t)(n0 + 64 + (t >> 2)) * K + kc * 8;

    f32x4 acc[4][4] = {};
    const int ra = wr * 64 + (lane & 15);
    const int rb = wc * 64 + (lane & 15);
    const int kos = (((lane >> 4) ^ (lane >> 1)) & 3) * 8;
    const int nIter = K >> 5;

    gload_lds16(gA0, As[0] + t * 8);
    gload_lds16(gA1, As[0] + 2048 + t * 8);
    gload_lds16(gB0, Bs[0] + t * 8);
    gload_lds16(gB1, Bs[0] + 2048 + t * 8);

    int cur = 0;
    for (int it = 0; it < nIter; ++it) {
        if (it + 1 < nIter) {
            const int k1 = (it + 1) << 5;
            gload_lds16(gA0 + k1, As[cur ^ 1] + t * 8);
            gload_lds16(gA1 + k1, As[cur ^ 1] + 2048 + t * 8);
            gload_lds16(gB0 + k1, Bs[cur ^ 1] + t * 8);
            gload_lds16(gB1 + k1, Bs[cur ^ 1] + 2048 + t * 8);
            asm volatile("s_waitcnt vmcnt(4)" ::: "memory");
        } else {
            asm volatile("s_waitcnt vmcnt(0)" ::: "memory");
        }
        __builtin_amdgcn_s_barrier();
        __builtin_amdgcn_sched_barrier(0);
        bf16x8 af[4], bfr[4];
#pragma unroll
        for (int i = 0; i < 4; ++i)
            af[i] = *(const bf16x8*)(As[cur] + (ra + i * 16) * 32 + kos);
#pragma unroll
        for (int j = 0; j < 4; ++j)
            bfr[j] = *(const bf16x8*)(Bs[cur] + (rb + j * 16) * 32 + kos);
        asm volatile("s_waitcnt lgkmcnt(0)" ::: "memory");
        __builtin_amdgcn_sched_barrier(0);
        __builtin_amdgcn_s_barrier();
#pragma unroll
        for (int i = 0; i < 4; ++i)
#pragma unroll
            for (int j = 0; j < 4; ++j)
                acc[i][j] = __builtin_amdgcn_mfma_f32_16x16x32_bf16(af[i], bfr[j], acc[i][j], 0, 0, 0);
        cur ^= 1;
    }

    const int colb = n0 + wc * 64 + (lane & 15);
    const int rowb = m0 + wr * 64 + ((lane >> 4) * 4);

    float* C = (float*)Cv;
    const u16* xr = (const u16*)extra;       // x1 bf16
#pragma unroll
    for (int j = 0; j < 4; ++j) {
        int col = colb + j * 16;
        float bj = bias[col], lj = extra2[col];
#pragma unroll
        for (int i = 0; i < 4; ++i) {
            int g  = grow0 + rowb + i * 16;   // 4-row pack never crosses batch
            int b  = g / HW, hw = g - b * HW;
            f32x4 o;
#pragma unroll
            for (int r = 0; r < 4; ++r)
                o[r] = bu2f(xr[(size_t)(g + r) * 256 + col]) + lj * (acc[i][j][r] + bj);
            *(f32x4*)(C + ((size_t)(b * 256 + col)) * HW + hw) = o;
        }
    }
}

// ---------------- fused attention + proj: one BLOCK per window ----------------
// R22-verified: swapped QK^T (lane-local softmax rows, 8 shuffles/lane),
// Pl stride 68, PV rows clamped <=48, weights-in-regs proj, no proj barriers.
__global__ __launch_bounds__(512) void k_attnproj(const u16* __restrict__ qkv,
        const u16* __restrict__ wpt, const float* __restrict__ pbias,
        u16* __restrict__ x1b) {
    __shared__ __align__(16) u16 U[8 * LWIN * PLS];   // 53,312 B
    const int wv = threadIdx.x >> 6, lane = threadIdx.x & 63;
    const int win = blockIdx.x, head = wv, wi = win & 63;
    const int rowbase = win * LWIN;
    const int g = lane >> 4, c = lane & 15, ko = g * 8;
    const u16* qb = qkv + (size_t)rowbase * 768 + head * 32;
    u16* pl = U + wv * (LWIN * PLS);

    bf16x8 vb[2][2];
#pragma unroll
    for (int j2 = 0; j2 < 2; ++j2) {
        int d = j2 * 16 + c;
#pragma unroll
        for (int h = 0; h < 2; ++h)
#pragma unroll
            for (int tt = 0; tt < 8; ++tt) {
                int k = h * 32 + ko + tt;
                u16 val = (k < LWIN) ? qb[(size_t)k * 768 + 512 + d] : (u16)0;
                vb[j2][h][tt] = __builtin_bit_cast(__bf16, val);
            }
    }

    bf16x8 qf[4], kf[4];
#pragma unroll
    for (int i = 0; i < 4; ++i) {
        int r0 = i * 16 + c; if (r0 > 48) r0 = 48;   // clamp: garbage rows unused
        qf[i] = *(const bf16x8*)(qb + (size_t)r0 * 768 + ko);
        kf[i] = *(const bf16x8*)(qb + (size_t)r0 * 768 + 256 + ko);
    }
    // --- S^T fragments: s[i][j] = K_j^T Q_i -> lane holds qrow=i*16+c,
    //     kcol = j*16 + g*4 + r  (m89 C/D layout with A=kf, B=qf) ---
    f32x4 s[4][4] = {};
    __builtin_amdgcn_s_setprio(1);
#pragma unroll
    for (int i = 0; i < 4; ++i)
#pragma unroll
        for (int j = 0; j < 4; ++j)
            s[i][j] = __builtin_amdgcn_mfma_f32_16x16x32_bf16(kf[j], qf[i], s[i][j], 0, 0, 0);
    __builtin_amdgcn_s_setprio(0);

    // --- masked softmax, lane-local rows ---
    const int wh7 = (wi >> 3) * 7, ww7 = (wi & 7) * 7;
    int idjn[4][4]; bool jokn[4][4];
#pragma unroll
    for (int j = 0; j < 4; ++j)
#pragma unroll
        for (int r = 0; r < 4; ++r) {
            int kcol = j * 16 + g * 4 + r;
            jokn[j][r] = kcol < LWIN;
            int p = jokn[j][r] ? kcol : 48;
            idjn[j][r] = region_of(wh7 + p / 7) * 3 + region_of(ww7 + p % 7);
        }
#pragma unroll
    for (int i = 0; i < 4; ++i) {
        int qrow = i * 16 + c;
        int p = qrow < LWIN ? qrow : 48;
        int idi = region_of(wh7 + p / 7) * 3 + region_of(ww7 + p % 7);
        float mx = -1e30f;
#pragma unroll
        for (int j = 0; j < 4; ++j)
#pragma unroll
            for (int r = 0; r < 4; ++r) {
                float tv = jokn[j][r] ? fmaf(s[i][j][r], 0.17677669529663687f,
                                             (idi == idjn[j][r]) ? 0.f : -100.f)
                                      : -1e30f;
                s[i][j][r] = tv;
                mx = fmaxf(mx, tv);
            }
        mx = fmaxf(mx, __shfl_xor(mx, 16));
        mx = fmaxf(mx, __shfl_xor(mx, 32));
        float ps = 0.f;
#pragma unroll
        for (int j = 0; j < 4; ++j)
#pragma unroll
            for (int r = 0; r < 4; ++r) {
                float e = __expf(s[i][j][r] - mx);
                s[i][j][r] = e; ps += e;
            }
        ps += __shfl_xor(ps, 16);
        ps += __shfl_xor(ps, 32);
        float inv = 1.f / ps;
        if (qrow < LWIN) {
#pragma unroll
            for (int j = 0; j < 4; ++j) {
                ushort4 st{f2bu(s[i][j][0] * inv), f2bu(s[i][j][1] * inv),
                           f2bu(s[i][j][2] * inv), f2bu(s[i][j][3] * inv)};
                *(ushort4*)(pl + qrow * PLS + j * 16 + g * 4) = st;
            }
        }
    }
    // per-wave pl: compiler-inserted lgkmcnt orders write->read within the wave

    // --- O = P V: rows clamped <=48, fragments via two b64 bf16x4 loads ---
    f32x4 o[4][2] = {};
    __builtin_amdgcn_s_setprio(1);
#pragma unroll
    for (int i = 0; i < 4; ++i) {
        int rowA = i * 16 + c; if (rowA > 48) rowA = 48;
        const u16* pr = pl + rowA * PLS + ko;
        bf16x4 a0 = *(const bf16x4*)(pr);
        bf16x4 a1 = *(const bf16x4*)(pr + 4);
        bf16x4 b0 = *(const bf16x4*)(pr + 32);
        bf16x4 b1 = *(const bf16x4*)(pr + 36);
        bf16x8 pa0 = __builtin_shufflevector(a0, a1, 0, 1, 2, 3, 4, 5, 6, 7);
        bf16x8 pa1 = __builtin_shufflevector(b0, b1, 0, 1, 2, 3, 4, 5, 6, 7);
#pragma unroll
        for (int j2 = 0; j2 < 2; ++j2) {
            o[i][j2] = __builtin_amdgcn_mfma_f32_16x16x32_bf16(pa0, vb[j2][0], o[i][j2], 0, 0, 0);
            o[i][j2] = __builtin_amdgcn_mfma_f32_16x16x32_bf16(pa1, vb[j2][1], o[i][j2], 0, 0, 0);
        }
    }
    __builtin_amdgcn_s_setprio(0);

    __syncthreads();        // all waves done reading Pl -> U reusable as o_t

    // --- weight slice -> registers (no swizzle: regs have no banks) ---
    bf16x8 wreg[8][2];
#pragma unroll
    for (int it = 0; it < 8; ++it)
#pragma unroll
        for (int j2 = 0; j2 < 2; ++j2)
            wreg[it][j2] = *(const bf16x8*)(wpt +
                (size_t)(wv * 32 + j2 * 16 + c) * 256 + it * 32 + ko);

    // --- o_t = U (64 x 264: row stride 528 B -> 2-way banks, free) ---
    u16* o_t = U;
#pragma unroll
    for (int i = 0; i < 4; ++i)
#pragma unroll
        for (int r = 0; r < 4; ++r) {
            int row = i * 16 + g * 4 + r;
            if (row < LWIN) {
#pragma unroll
                for (int j2 = 0; j2 < 2; ++j2)
                    o_t[row * 264 + head * 32 + j2 * 16 + c] = f2bu(o[i][j2][r]);
            }
        }
    __syncthreads();        // o_t complete (rows >= 49 stale-garbage: discarded)

    // --- proj: 8 x {4 ds_read + 8 MFMA}, no barriers, weights in regs ---
    f32x4 acc2[4][2] = {};
#pragma unroll
    for (int it = 0; it < 8; ++it) {
        bf16x8 af[4];
#pragma unroll
        for (int i = 0; i < 4; ++i)
            af[i] = *(const bf16x8*)(o_t + (i * 16 + c) * 264 + it * 32 + ko);
        __builtin_amdgcn_s_setprio(1);
#pragma unroll
        for (int i = 0; i < 4; ++i)
#pragma unroll
            for (int j2 = 0; j2 < 2; ++j2)
                acc2[i][j2] = __builtin_amdgcn_mfma_f32_16x16x32_bf16(af[i], wreg[it][j2], acc2[i][j2], 0, 0, 0);
        __builtin_amdgcn_s_setprio(0);
    }

    // --- epilogue: scatter to x1b (proj_out) via row2tok, + bias ---
#pragma unroll
    for (int j2 = 0; j2 < 2; ++j2) {
        int col = wv * 32 + j2 * 16 + c;
        float bj = pbias[col];
#pragma unroll
        for (int i = 0; i < 4; ++i)
#pragma unroll
            for (int r = 0; r < 4; ++r) {
                int row = i * 16 + g * 4 + r;
                if (row < LWIN) {
                    int tok = row2tok(rowbase + row);
                    x1b[(size_t)tok * 256 + col] = f2bu(acc2[i][j2][r] + bj);
                }
            }
    }
}

extern "C" void kernel_launch(void* const* d_in, const int* in_sizes, int n_in,
                              void* d_out, int out_size, void* d_ws, size_t ws_size,
                              hipStream_t stream) {
    const float* x      = (const float*)d_in[0];
    const float* ln1_g  = (const float*)d_in[1];
    const float* ln1_b  = (const float*)d_in[2];
    const float* ln2_g  = (const float*)d_in[3];
    const float* ln2_b  = (const float*)d_in[4];
    const float* qkv_w  = (const float*)d_in[5];
    const float* qkv_b  = (const float*)d_in[6];
    const float* proj_w = (const float*)d_in[7];
    const float* proj_b = (const float*)d_in[8];
    const float* ffn_w1 = (const float*)d_in[9];
    const float* ffn_b1 = (const float*)d_in[10];
    const float* ffn_w2 = (const float*)d_in[11];
    const float* ffn_b2 = (const float*)d_in[12];
    const float* lscale = (const float*)d_in[13];

    // workspace: total 104,333,312 B (layout unchanged since R6)
    char* wsb = (char*)d_ws;
    u16* wqt  = (u16*)(wsb);
    u16* wpt  = (u16*)(wsb + 393216);
    u16* w1t  = (u16*)(wsb + 524288);
    u16* w2t  = (u16*)(wsb + 1048576);
    u16* P    = (u16*)(wsb + 1572864);
    char* Qb  = wsb + 27262976;
    u16* qkvb = (u16*)Qb;
    u16* x1b  = (u16*)Qb;
    u16* f1c  = (u16*)(Qb + 25690112);

    k_wconv_all<<<768, 256, 0, stream>>>(qkv_w, wqt, proj_w, wpt, ffn_w1, w1t, ffn_w2, w2t);

    k_ln1<<<16 * 98, 256, 0, stream>>>(x, ln1_g, ln1_b, P);
    // qkv: 196 m-blocks x 6 n-blocks, XCD-swizzled 1-D grid (1176 % 8 == 0)
    k_mgemm256<0><<<1176, 512, 0, stream>>>(P, wqt, qkv_b, qkvb, 256, 768, 6);
    // fused attention + proj -> proj_out (x1b, token-scattered bf16)
    k_attnproj<<<1024, 512, 0, stream>>>(qkvb, wpt, proj_b, x1b);
    // x1 = proj_out + transpose(x) (in-place), h2 = LN2(x1) -> P
    k_ln2t<<<16 * 98, 256, 0, stream>>>(x, x1b, ln2_g, ln2_b, P);
    for (int c = 0; c < 2; ++c) {
        // ffn1: 98 x 8 = 784 (784 % 8 == 0)
        k_mgemm256<2><<<784, 512, 0, stream>>>(P + (size_t)c * FCH * 256, w1t, ffn_b1,
                                               f1c, 256, 1024, 8);
        // ffn2: 196 x 2 = 392 (392 % 8 == 0)
        k_mgemm128<3><<<392, 256, 0, stream>>>(f1c, w2t, ffn_b2, d_out, 1024, 256,
                                               x1b, lscale, c * FCH, 2);
    }
}

// Round 24
// 228.910 us; speedup vs baseline: 1.4069x; 1.0077x over previous
//
#include <hip/hip_runtime.h>
#include <hip/hip_bf16.h>
#include <math.h>

typedef unsigned short u16;
typedef __bf16 bf16x8 __attribute__((ext_vector_type(8)));
typedef __bf16 bf16x4 __attribute__((ext_vector_type(4)));
typedef float  f32x4  __attribute__((ext_vector_type(4)));

#define DIMC 256
#define QSZ  56
#define WSZ  7
#define SSZ  3
#define LWIN 49
#define NWIN 64
#define HW   3136          // 56*56
#define NTOK 50176         // 16*3136
#define FFWD 1024
#define FCH  25088         // NTOK/2 ffn chunk rows
#define PLS  68            // Pl row stride u16: 136 B (b64-aligned); 8*49*68*2 = 53,312 B

__device__ __forceinline__ u16 f2bu(float f) {
    __hip_bfloat16 h = __float2bfloat16(f);
    return __builtin_bit_cast(u16, h);
}
__device__ __forceinline__ float bu2f(u16 u) {
    unsigned v = (unsigned)u << 16;
    return __builtin_bit_cast(float, v);
}
__device__ __forceinline__ void gload_lds16(const void* g, void* l) {
    __builtin_amdgcn_global_load_lds((const __attribute__((address_space(1))) void*)g,
                                     (__attribute__((address_space(3))) void*)l, 16, 0, 0);
}

// XCD-bijective swizzle (m204): nwg % 8 == 0 required.
__device__ __forceinline__ int xcd_swz(int flat, int nwg) {
    int q = nwg >> 3;
    return (flat & 7) * q + (flat >> 3);
}

__device__ __forceinline__ int region_of(int h) {
    return (h < 49) ? 0 : ((h < 53) ? 1 : 2);
}

// partitioned row m = ((b*64 + wi)*49 + p) -> flat token index (with roll by -3)
__device__ __forceinline__ int row2tok(int m) {
    int b  = m / (NWIN * LWIN);
    int r  = m - b * (NWIN * LWIN);
    int wi = r / LWIN;
    int p  = r - wi * LWIN;
    int wh = wi >> 3, ww = wi & 7;
    int ph = p / 7,   pw = p - ph * 7;
    int hr = wh * 7 + ph, wr = ww * 7 + pw;
    int hs = hr + SSZ; if (hs >= QSZ) hs -= QSZ;
    int ws2 = wr + SSZ; if (ws2 >= QSZ) ws2 -= QSZ;
    return b * HW + hs * QSZ + ws2;
}

// ---------------- merged weight transpose + bf16 convert (4 weights) ----------
__device__ __forceinline__ void wconv_body(const float* __restrict__ W,
        u16* __restrict__ Wt, int K, int N, int bx, int by, int t) {
    __shared__ float tile[32][33];
    int k0 = bx * 32, n0 = by * 32;
    int tx = t & 31, ty = t >> 5;
    for (int kk = ty; kk < 32; kk += 8)
        tile[kk][tx] = W[(size_t)(k0 + kk) * N + n0 + tx];
    __syncthreads();
    for (int nn = ty; nn < 32; nn += 8)
        Wt[(size_t)(n0 + nn) * K + k0 + tx] = f2bu(tile[tx][nn]);
}

__global__ __launch_bounds__(256) void k_wconv_all(
        const float* __restrict__ qkv_w, u16* __restrict__ wqt,
        const float* __restrict__ proj_w, u16* __restrict__ wpt,
        const float* __restrict__ ffn_w1, u16* __restrict__ w1t,
        const float* __restrict__ ffn_w2, u16* __restrict__ w2t) {
    int b = blockIdx.x, t = threadIdx.x;
    if (b < 192)        wconv_body(qkv_w, wqt, 256, 768, b & 7, b >> 3, t);
    else if (b < 256) { b -= 192; wconv_body(proj_w, wpt, 256, 256,  b & 7, b >> 3, t); }
    else if (b < 512) { b -= 256; wconv_body(ffn_w1, w1t, 256, 1024, b & 7, b >> 3, t); }
    else              { b -= 512; wconv_body(ffn_w2, w2t, 1024, 256, b & 31, b >> 5, t); }
}

// ---------------- K1: BCHW -> token-major transpose + LN1 -> bf16 -------------
// Reduce loop reads ROTATED per sub-lane (R23-verified: 8-way -> ~2-way banks).
__global__ __launch_bounds__(256) void k_ln1(const float* __restrict__ x,
        const float* __restrict__ g, const float* __restrict__ be,
        u16* __restrict__ hln) {
    __shared__ float tile[32][257];
    __shared__ float msh[32], rsh[32];
    int blk = blockIdx.x;            // 16 * 98
    int b   = blk / 98;
    int hw0 = (blk - b * 98) * 32;
    int t   = threadIdx.x;
    int tx  = t & 31, ty = t >> 5;
    for (int c = ty; c < 256; c += 8)
        tile[tx][c] = x[(size_t)(b * 256 + c) * HW + hw0 + tx];
    __syncthreads();
    int row = t >> 3, sub = t & 7;
    float s = 0.f, sq = 0.f;
    for (int i = 0; i < 32; ++i) {
        int cc = sub * 32 + ((i + sub * 4) & 31);
        float v = tile[row][cc]; s += v; sq += v * v;
    }
    for (int o = 4; o; o >>= 1) { s += __shfl_down(s, o, 8); sq += __shfl_down(sq, o, 8); }
    if (sub == 0) {
        float m   = s * (1.f / 256.f);
        float var = sq * (1.f / 256.f) - m * m;
        msh[row] = m; rsh[row] = rsqrtf(var + 1e-5f);
    }
    __syncthreads();
    float gg = g[t], bb = be[t];
    for (int r2 = 0; r2 < 32; ++r2) {
        float v = tile[r2][t];
        hln[(size_t)(b * HW + hw0 + r2) * 256 + t] = f2bu((v - msh[r2]) * rsh[r2] * gg + bb);
    }
}

// ---------------- LN2 + residual: x1 = proj_out + transpose(x); h2 = LN(x1) ---
__global__ __launch_bounds__(256) void k_ln2t(const float* __restrict__ x,
        u16* __restrict__ x1b, const float* __restrict__ g,
        const float* __restrict__ be, u16* __restrict__ h2) {
    __shared__ float tile[32][257];
    __shared__ float msh[32], rsh[32];
    int blk = blockIdx.x;            // 16 * 98
    int b   = blk / 98;
    int hw0 = (blk - b * 98) * 32;
    int t   = threadIdx.x;
    int tx  = t & 31, ty = t >> 5;
    for (int c = ty; c < 256; c += 8)
        tile[tx][c] = x[(size_t)(b * 256 + c) * HW + hw0 + tx];
    __syncthreads();
    size_t base = (size_t)b * HW + hw0;
    for (int r2 = 0; r2 < 32; ++r2) {
        float v = tile[r2][t] + bu2f(x1b[(base + r2) * 256 + t]);
        tile[r2][t] = v;
        x1b[(base + r2) * 256 + t] = f2bu(v);
    }
    __syncthreads();
    int row = t >> 3, sub = t & 7;
    float s = 0.f, sq = 0.f;
    for (int i = 0; i < 32; ++i) {
        int cc = sub * 32 + ((i + sub * 4) & 31);
        float v = tile[row][cc]; s += v; sq += v * v;
    }
    for (int o = 4; o; o >>= 1) { s += __shfl_down(s, o, 8); sq += __shfl_down(sq, o, 8); }
    if (sub == 0) {
        float m   = s * (1.f / 256.f);
        float var = sq * (1.f / 256.f) - m * m;
        msh[row] = m; rsh[row] = rsqrtf(var + 1e-5f);
    }
    __syncthreads();
    float gg = g[t], bb = be[t];
    for (int r2 = 0; r2 < 32; ++r2) {
        float v = tile[r2][t];
        h2[(base + r2) * 256 + t] = f2bu((v - msh[r2]) * rsh[r2] * gg + bb);
    }
}

// ---------------- MFMA GEMM, 256x128 tile, 512 thr (qkv / ffn1) ---------------
// R13-verified loop + T1 XCD grid (verified R17: -28 us).
template<int MODE>
__global__ __launch_bounds__(512) void k_mgemm256(
        const u16* __restrict__ A, const u16* __restrict__ Bt,
        const float* __restrict__ bias, void* __restrict__ Cv, int K, int N,
        int gy) {
    __shared__ __align__(16) u16 As[2][256 * 32];
    __shared__ __align__(16) u16 Bs[2][128 * 32];
    const int swz = xcd_swz(blockIdx.x, gridDim.x);
    const int mb = swz / gy, nb = swz - mb * gy;
    const int m0 = mb * 256, n0 = nb * 128;
    const int t = threadIdx.x, lane = t & 63;
    const int wv = t >> 6, wr = wv >> 1, wc = wv & 1;

    const int kc = (t & 3) ^ ((t >> 3) & 3);
    int ar0 = m0 + (t >> 2), ar1 = m0 + 128 + (t >> 2);
    if (MODE == 0) { ar0 = row2tok(ar0); ar1 = row2tok(ar1); }
    const u16* gA0 = A  + (size_t)ar0 * K + kc * 8;
    const u16* gA1 = A  + (size_t)ar1 * K + kc * 8;
    const u16* gB0 = Bt + (size_t)(n0 + (t >> 2)) * K + kc * 8;

    f32x4 acc[4][4] = {};
    const int ra = wr * 64 + (lane & 15);
    const int rb = wc * 64 + (lane & 15);
    const int kos = (((lane >> 4) ^ (lane >> 1)) & 3) * 8;
    const int nIter = K >> 5;

    gload_lds16(gA0, As[0] + t * 8);
    gload_lds16(gA1, As[0] + 4096 + t * 8);
    gload_lds16(gB0, Bs[0] + t * 8);

    int cur = 0;
    for (int it = 0; it < nIter; ++it) {
        if (it + 1 < nIter) {
            const int k1 = (it + 1) << 5;
            gload_lds16(gA0 + k1, As[cur ^ 1] + t * 8);
            gload_lds16(gA1 + k1, As[cur ^ 1] + 4096 + t * 8);
            gload_lds16(gB0 + k1, Bs[cur ^ 1] + t * 8);
            asm volatile("s_waitcnt vmcnt(3)" ::: "memory");
        } else {
            asm volatile("s_waitcnt vmcnt(0)" ::: "memory");
        }
        __builtin_amdgcn_s_barrier();
        __builtin_amdgcn_sched_barrier(0);
        bf16x8 af[4], bfr[4];
#pragma unroll
        for (int i = 0; i < 4; ++i)
            af[i] = *(const bf16x8*)(As[cur] + (ra + i * 16) * 32 + kos);
#pragma unroll
        for (int j = 0; j < 4; ++j)
            bfr[j] = *(const bf16x8*)(Bs[cur] + (rb + ((j & 1) * 16 + (j >> 1) * 32)) * 32 + kos);
        asm volatile("s_waitcnt lgkmcnt(0)" ::: "memory");
        __builtin_amdgcn_sched_barrier(0);
        __builtin_amdgcn_s_barrier();
#pragma unroll
        for (int i = 0; i < 4; ++i)
#pragma unroll
            for (int j = 0; j < 4; ++j)
                acc[i][j] = __builtin_amdgcn_mfma_f32_16x16x32_bf16(af[i], bfr[j], acc[i][j], 0, 0, 0);
        cur ^= 1;
    }

    const int rowb = m0 + wr * 64 + ((lane >> 4) * 4);
    u16* Cb = (u16*)Cv;
#pragma unroll
    for (int j = 0; j < 4; ++j) {
        int col = n0 + wc * 64 + ((j & 1) * 16 + (j >> 1) * 32) + (lane & 15);
        float bj = bias[col];
#pragma unroll
        for (int i = 0; i < 4; ++i) {
            int rw = rowb + i * 16;
#pragma unroll
            for (int r = 0; r < 4; ++r) {
                float v = acc[i][j][r] + bj;
                if (MODE == 2) v = fmaxf(v, 0.f);
                Cb[(size_t)(rw + r) * N + col] = f2bu(v);
            }
        }
    }
}

// ---------------- MFMA GEMM, 128x128 tile, 256 thr (ffn2) ---------------------
template<int MODE>
__global__ __launch_bounds__(256) void k_mgemm128(
        const u16* __restrict__ A, const u16* __restrict__ Bt,
        const float* __restrict__ bias, void* __restrict__ Cv,
        int K, int N, const void* __restrict__ extra,
        const float* __restrict__ extra2, int grow0, int gy) {
    __shared__ __align__(16) u16 As[2][128 * 32];
    __shared__ __align__(16) u16 Bs[2][128 * 32];
    const int swz = xcd_swz(blockIdx.x, gridDim.x);
    const int mb = swz / gy, nb = swz - mb * gy;
    const int m0 = mb * 128, n0 = nb * 128;
    const int t = threadIdx.x, lane = t & 63;
    const int wv = t >> 6, wr = wv >> 1, wc = wv & 1;

    const int kc = (t & 3) ^ ((t >> 3) & 3);
    const u16* gA0 = A  + (size_t)(m0 + (t >> 2)) * K + kc * 8;
    const u16* gA1 = A  + (size_t)(m0 + 64 + (t >> 2)) * K + kc * 8;
    const u16* gB0 = Bt + (size_t)(n0 + (t >> 2)) * K + kc * 8;
    const u16* gB1 = Bt + (size_t)(n0 + 64 + (t >> 2)) * K + kc * 8;

    f32x4 acc[4][4] = {};
    const int ra = wr * 64 + (lane & 15);
    const int rb = wc * 64 + (lane & 15);
    const int kos = (((lane >> 4) ^ (lane >> 1)) & 3) * 8;
    const int nIter = K >> 5;

    gload_lds16(gA0, As[0] + t * 8);
    gload_lds16(gA1, As[0] + 2048 + t * 8);
    gload_lds16(gB0, Bs[0] + t * 8);
    gload_lds16(gB1, Bs[0] + 2048 + t * 8);

    int cur = 0;
    for (int it = 0; it < nIter; ++it) {
        if (it + 1 < nIter) {
            const int k1 = (it + 1) << 5;
            gload_lds16(gA0 + k1, As[cur ^ 1] + t * 8);
            gload_lds16(gA1 + k1, As[cur ^ 1] + 2048 + t * 8);
            gload_lds16(gB0 + k1, Bs[cur ^ 1] + t * 8);
            gload_lds16(gB1 + k1, Bs[cur ^ 1] + 2048 + t * 8);
            asm volatile("s_waitcnt vmcnt(4)" ::: "memory");
        } else {
            asm volatile("s_waitcnt vmcnt(0)" ::: "memory");
        }
        __builtin_amdgcn_s_barrier();
        __builtin_amdgcn_sched_barrier(0);
        bf16x8 af[4], bfr[4];
#pragma unroll
        for (int i = 0; i < 4; ++i)
            af[i] = *(const bf16x8*)(As[cur] + (ra + i * 16) * 32 + kos);
#pragma unroll
        for (int j = 0; j < 4; ++j)
            bfr[j] = *(const bf16x8*)(Bs[cur] + (rb + j * 16) * 32 + kos);
        asm volatile("s_waitcnt lgkmcnt(0)" ::: "memory");
        __builtin_amdgcn_sched_barrier(0);
        __builtin_amdgcn_s_barrier();
#pragma unroll
        for (int i = 0; i < 4; ++i)
#pragma unroll
            for (int j = 0; j < 4; ++j)
                acc[i][j] = __builtin_amdgcn_mfma_f32_16x16x32_bf16(af[i], bfr[j], acc[i][j], 0, 0, 0);
        cur ^= 1;
    }

    const int colb = n0 + wc * 64 + (lane & 15);
    const int rowb = m0 + wr * 64 + ((lane >> 4) * 4);

    float* C = (float*)Cv;
    const u16* xr = (const u16*)extra;       // x1 bf16
#pragma unroll
    for (int j = 0; j < 4; ++j) {
        int col = colb + j * 16;
        float bj = bias[col], lj = extra2[col];
#pragma unroll
        for (int i = 0; i < 4; ++i) {
            int g  = grow0 + rowb + i * 16;   // 4-row pack never crosses batch
            int b  = g / HW, hw = g - b * HW;
            f32x4 o;
#pragma unroll
            for (int r = 0; r < 4; ++r)
                o[r] = bu2f(xr[(size_t)(g + r) * 256 + col]) + lj * (acc[i][j][r] + bj);
            *(f32x4*)(C + ((size_t)(b * 256 + col)) * HW + hw) = o;
        }
    }
}

// ---------------- fused attention + proj: one BLOCK per window ----------------
// R23-verified structure (swapped QK^T lane-local softmax, Pl stride 68,
// PV rows clamped <=48, weights-in-regs proj) + NEW: per-block token table
// tokT[49] computed ONCE (threads 0..48, between the two existing syncs) —
// replaces 8192 redundant row2tok calls/block (~400 VALU ops/lane) with
// LDS reads in the epilogue.
__global__ __launch_bounds__(512) void k_attnproj(const u16* __restrict__ qkv,
        const u16* __restrict__ wpt, const float* __restrict__ pbias,
        u16* __restrict__ x1b) {
    __shared__ __align__(16) u16 U[8 * LWIN * PLS];   // 53,312 B
    __shared__ int tokT[64];                          // +256 B (53,568 tot)
    const int wv = threadIdx.x >> 6, lane = threadIdx.x & 63;
    const int win = blockIdx.x, head = wv, wi = win & 63;
    const int rowbase = win * LWIN;
    const int g = lane >> 4, c = lane & 15, ko = g * 8;
    const u16* qb = qkv + (size_t)rowbase * 768 + head * 32;
    u16* pl = U + wv * (LWIN * PLS);

    bf16x8 vb[2][2];
#pragma unroll
    for (int j2 = 0; j2 < 2; ++j2) {
        int d = j2 * 16 + c;
#pragma unroll
        for (int h = 0; h < 2; ++h)
#pragma unroll
            for (int tt = 0; tt < 8; ++tt) {
                int k = h * 32 + ko + tt;
                u16 val = (k < LWIN) ? qb[(size_t)k * 768 + 512 + d] : (u16)0;
                vb[j2][h][tt] = __builtin_bit_cast(__bf16, val);
            }
    }

    bf16x8 qf[4], kf[4];
#pragma unroll
    for (int i = 0; i < 4; ++i) {
        int r0 = i * 16 + c; if (r0 > 48) r0 = 48;   // clamp: garbage rows unused
        qf[i] = *(const bf16x8*)(qb + (size_t)r0 * 768 + ko);
        kf[i] = *(const bf16x8*)(qb + (size_t)r0 * 768 + 256 + ko);
    }
    // --- S^T fragments: s[i][j] = K_j^T Q_i -> lane holds qrow=i*16+c,
    //     kcol = j*16 + g*4 + r  (m89 C/D layout with A=kf, B=qf) ---
    f32x4 s[4][4] = {};
    __builtin_amdgcn_s_setprio(1);
#pragma unroll
    for (int i = 0; i < 4; ++i)
#pragma unroll
        for (int j = 0; j < 4; ++j)
            s[i][j] = __builtin_amdgcn_mfma_f32_16x16x32_bf16(kf[j], qf[i], s[i][j], 0, 0, 0);
    __builtin_amdgcn_s_setprio(0);

    // --- masked softmax, lane-local rows ---
    const int wh7 = (wi >> 3) * 7, ww7 = (wi & 7) * 7;
    int idjn[4][4]; bool jokn[4][4];
#pragma unroll
    for (int j = 0; j < 4; ++j)
#pragma unroll
        for (int r = 0; r < 4; ++r) {
            int kcol = j * 16 + g * 4 + r;
            jokn[j][r] = kcol < LWIN;
            int p = jokn[j][r] ? kcol : 48;
            idjn[j][r] = region_of(wh7 + p / 7) * 3 + region_of(ww7 + p % 7);
        }
#pragma unroll
    for (int i = 0; i < 4; ++i) {
        int qrow = i * 16 + c;
        int p = qrow < LWIN ? qrow : 48;
        int idi = region_of(wh7 + p / 7) * 3 + region_of(ww7 + p % 7);
        float mx = -1e30f;
#pragma unroll
        for (int j = 0; j < 4; ++j)
#pragma unroll
            for (int r = 0; r < 4; ++r) {
                float tv = jokn[j][r] ? fmaf(s[i][j][r], 0.17677669529663687f,
                                             (idi == idjn[j][r]) ? 0.f : -100.f)
                                      : -1e30f;
                s[i][j][r] = tv;
                mx = fmaxf(mx, tv);
            }
        mx = fmaxf(mx, __shfl_xor(mx, 16));
        mx = fmaxf(mx, __shfl_xor(mx, 32));
        float ps = 0.f;
#pragma unroll
        for (int j = 0; j < 4; ++j)
#pragma unroll
            for (int r = 0; r < 4; ++r) {
                float e = __expf(s[i][j][r] - mx);
                s[i][j][r] = e; ps += e;
            }
        ps += __shfl_xor(ps, 16);
        ps += __shfl_xor(ps, 32);
        float inv = 1.f / ps;
        if (qrow < LWIN) {
#pragma unroll
            for (int j = 0; j < 4; ++j) {
                ushort4 st{f2bu(s[i][j][0] * inv), f2bu(s[i][j][1] * inv),
                           f2bu(s[i][j][2] * inv), f2bu(s[i][j][3] * inv)};
                *(ushort4*)(pl + qrow * PLS + j * 16 + g * 4) = st;
            }
        }
    }
    // per-wave pl: compiler-inserted lgkmcnt orders write->read within the wave

    // --- O = P V: rows clamped <=48, fragments via two b64 bf16x4 loads ---
    f32x4 o[4][2] = {};
    __builtin_amdgcn_s_setprio(1);
#pragma unroll
    for (int i = 0; i < 4; ++i) {
        int rowA = i * 16 + c; if (rowA > 48) rowA = 48;
        const u16* pr = pl + rowA * PLS + ko;
        bf16x4 a0 = *(const bf16x4*)(pr);
        bf16x4 a1 = *(const bf16x4*)(pr + 4);
        bf16x4 b0 = *(const bf16x4*)(pr + 32);
        bf16x4 b1 = *(const bf16x4*)(pr + 36);
        bf16x8 pa0 = __builtin_shufflevector(a0, a1, 0, 1, 2, 3, 4, 5, 6, 7);
        bf16x8 pa1 = __builtin_shufflevector(b0, b1, 0, 1, 2, 3, 4, 5, 6, 7);
#pragma unroll
        for (int j2 = 0; j2 < 2; ++j2) {
            o[i][j2] = __builtin_amdgcn_mfma_f32_16x16x32_bf16(pa0, vb[j2][0], o[i][j2], 0, 0, 0);
            o[i][j2] = __builtin_amdgcn_mfma_f32_16x16x32_bf16(pa1, vb[j2][1], o[i][j2], 0, 0, 0);
        }
    }
    __builtin_amdgcn_s_setprio(0);

    __syncthreads();        // all waves done reading Pl -> U reusable as o_t

    // --- token table: 49 row2tok calls per BLOCK (was 16 per LANE) ---
    if (threadIdx.x < LWIN)
        tokT[threadIdx.x] = row2tok(rowbase + threadIdx.x);

    // --- weight slice -> registers (no swizzle: regs have no banks) ---
    bf16x8 wreg[8][2];
#pragma unroll
    for (int it = 0; it < 8; ++it)
#pragma unroll
        for (int j2 = 0; j2 < 2; ++j2)
            wreg[it][j2] = *(const bf16x8*)(wpt +
                (size_t)(wv * 32 + j2 * 16 + c) * 256 + it * 32 + ko);

    // --- o_t = U (64 x 264: row stride 528 B -> 2-way banks, free) ---
    u16* o_t = U;
#pragma unroll
    for (int i = 0; i < 4; ++i)
#pragma unroll
        for (int r = 0; r < 4; ++r) {
            int row = i * 16 + g * 4 + r;
            if (row < LWIN) {
#pragma unroll
                for (int j2 = 0; j2 < 2; ++j2)
                    o_t[row * 264 + head * 32 + j2 * 16 + c] = f2bu(o[i][j2][r]);
            }
        }
    __syncthreads();        // o_t + tokT complete (rows >= 49 garbage: discarded)

    // --- proj: 8 x {4 ds_read + 8 MFMA}, no barriers, weights in regs ---
    f32x4 acc2[4][2] = {};
#pragma unroll
    for (int it = 0; it < 8; ++it) {
        bf16x8 af[4];
#pragma unroll
        for (int i = 0; i < 4; ++i)
            af[i] = *(const bf16x8*)(o_t + (i * 16 + c) * 264 + it * 32 + ko);
        __builtin_amdgcn_s_setprio(1);
#pragma unroll
        for (int i = 0; i < 4; ++i)
#pragma unroll
            for (int j2 = 0; j2 < 2; ++j2)
                acc2[i][j2] = __builtin_amdgcn_mfma_f32_16x16x32_bf16(af[i], wreg[it][j2], acc2[i][j2], 0, 0, 0);
        __builtin_amdgcn_s_setprio(0);
    }

    // --- epilogue: scatter to x1b via tokT (LDS), + bias ---
#pragma unroll
    for (int j2 = 0; j2 < 2; ++j2) {
        int col = wv * 32 + j2 * 16 + c;
        float bj = pbias[col];
#pragma unroll
        for (int i = 0; i < 4; ++i)
#pragma unroll
            for (int r = 0; r < 4; ++r) {
                int row = i * 16 + g * 4 + r;
                if (row < LWIN) {
                    int tok = tokT[row];
                    x1b[(size_t)tok * 256 + col] = f2bu(acc2[i][j2][r] + bj);
                }
            }
    }
}

extern "C" void kernel_launch(void* const* d_in, const int* in_sizes, int n_in,
                              void* d_out, int out_size, void* d_ws, size_t ws_size,
                              hipStream_t stream) {
    const float* x      = (const float*)d_in[0];
    const float* ln1_g  = (const float*)d_in[1];
    const float* ln1_b  = (const float*)d_in[2];
    const float* ln2_g  = (const float*)d_in[3];
    const float* ln2_b  = (const float*)d_in[4];
    const float* qkv_w  = (const float*)d_in[5];
    const float* qkv_b  = (const float*)d_in[6];
    const float* proj_w = (const float*)d_in[7];
    const float* proj_b = (const float*)d_in[8];
    const float* ffn_w1 = (const float*)d_in[9];
    const float* ffn_b1 = (const float*)d_in[10];
    const float* ffn_w2 = (const float*)d_in[11];
    const float* ffn_b2 = (const float*)d_in[12];
    const float* lscale = (const float*)d_in[13];

    // workspace: total 104,333,312 B (layout unchanged since R6)
    char* wsb = (char*)d_ws;
    u16* wqt  = (u16*)(wsb);
    u16* wpt  = (u16*)(wsb + 393216);
    u16* w1t  = (u16*)(wsb + 524288);
    u16* w2t  = (u16*)(wsb + 1048576);
    u16* P    = (u16*)(wsb + 1572864);
    char* Qb  = wsb + 27262976;
    u16* qkvb = (u16*)Qb;
    u16* x1b  = (u16*)Qb;
    u16* f1c  = (u16*)(Qb + 25690112);

    k_wconv_all<<<768, 256, 0, stream>>>(qkv_w, wqt, proj_w, wpt, ffn_w1, w1t, ffn_w2, w2t);

    k_ln1<<<16 * 98, 256, 0, stream>>>(x, ln1_g, ln1_b, P);
    // qkv: 196 m-blocks x 6 n-blocks, XCD-swizzled 1-D grid (1176 % 8 == 0)
    k_mgemm256<0><<<1176, 512, 0, stream>>>(P, wqt, qkv_b, qkvb, 256, 768, 6);
    // fused attention + proj -> proj_out (x1b, token-scattered bf16)
    k_attnproj<<<1024, 512, 0, stream>>>(qkvb, wpt, proj_b, x1b);
    // x1 = proj_out + transpose(x) (in-place), h2 = LN2(x1) -> P
    k_ln2t<<<16 * 98, 256, 0, stream>>>(x, x1b, ln2_g, ln2_b, P);
    for (int c = 0; c < 2; ++c) {
        // ffn1: 98 x 8 = 784 (784 % 8 == 0)
        k_mgemm256<2><<<784, 512, 0, stream>>>(P + (size_t)c * FCH * 256, w1t, ffn_b1,
                                               f1c, 256, 1024, 8);
        // ffn2: 196 x 2 = 392 (392 % 8 == 0)
        k_mgemm128<3><<<392, 256, 0, stream>>>(f1c, w2t, ffn_b2, d_out, 1024, 256,
                                               x1b, lscale, c * FCH, 2);
    }
}

// Round 25
// 228.727 us; speedup vs baseline: 1.4080x; 1.0008x over previous
//
#include <hip/hip_runtime.h>
#include <hip/hip_bf16.h>
#include <math.h>

typedef unsigned short u16;
typedef __bf16 bf16x8 __attribute__((ext_vector_type(8)));
typedef __bf16 bf16x4 __attribute__((ext_vector_type(4)));
typedef float  f32x4  __attribute__((ext_vector_type(4)));

#define DIMC 256
#define QSZ  56
#define WSZ  7
#define SSZ  3
#define LWIN 49
#define NWIN 64
#define HW   3136          // 56*56
#define NTOK 50176         // 16*3136
#define FFWD 1024
#define FCH  25088         // NTOK/2 ffn chunk rows
#define PLS  68            // Pl row stride u16: 136 B (b64-aligned); 8*49*68*2 = 53,312 B

__device__ __forceinline__ u16 f2bu(float f) {
    __hip_bfloat16 h = __float2bfloat16(f);
    return __builtin_bit_cast(u16, h);
}
__device__ __forceinline__ float bu2f(u16 u) {
    unsigned v = (unsigned)u << 16;
    return __builtin_bit_cast(float, v);
}
__device__ __forceinline__ void gload_lds16(const void* g, void* l) {
    __builtin_amdgcn_global_load_lds((const __attribute__((address_space(1))) void*)g,
                                     (__attribute__((address_space(3))) void*)l, 16, 0, 0);
}

// XCD-bijective swizzle (m204): nwg % 8 == 0 required.
__device__ __forceinline__ int xcd_swz(int flat, int nwg) {
    int q = nwg >> 3;
    return (flat & 7) * q + (flat >> 3);
}

__device__ __forceinline__ int region_of(int h) {
    return (h < 49) ? 0 : ((h < 53) ? 1 : 2);
}

// partitioned row m = ((b*64 + wi)*49 + p) -> flat token index (with roll by -3)
__device__ __forceinline__ int row2tok(int m) {
    int b  = m / (NWIN * LWIN);
    int r  = m - b * (NWIN * LWIN);
    int wi = r / LWIN;
    int p  = r - wi * LWIN;
    int wh = wi >> 3, ww = wi & 7;
    int ph = p / 7,   pw = p - ph * 7;
    int hr = wh * 7 + ph, wr = ww * 7 + pw;
    int hs = hr + SSZ; if (hs >= QSZ) hs -= QSZ;
    int ws2 = wr + SSZ; if (ws2 >= QSZ) ws2 -= QSZ;
    return b * HW + hs * QSZ + ws2;
}

// ---------------- merged weight transpose + bf16 convert (4 weights) ----------
__device__ __forceinline__ void wconv_body(const float* __restrict__ W,
        u16* __restrict__ Wt, int K, int N, int bx, int by, int t) {
    __shared__ float tile[32][33];
    int k0 = bx * 32, n0 = by * 32;
    int tx = t & 31, ty = t >> 5;
    for (int kk = ty; kk < 32; kk += 8)
        tile[kk][tx] = W[(size_t)(k0 + kk) * N + n0 + tx];
    __syncthreads();
    for (int nn = ty; nn < 32; nn += 8)
        Wt[(size_t)(n0 + nn) * K + k0 + tx] = f2bu(tile[tx][nn]);
}

__global__ __launch_bounds__(256) void k_wconv_all(
        const float* __restrict__ qkv_w, u16* __restrict__ wqt,
        const float* __restrict__ proj_w, u16* __restrict__ wpt,
        const float* __restrict__ ffn_w1, u16* __restrict__ w1t,
        const float* __restrict__ ffn_w2, u16* __restrict__ w2t) {
    int b = blockIdx.x, t = threadIdx.x;
    if (b < 192)        wconv_body(qkv_w, wqt, 256, 768, b & 7, b >> 3, t);
    else if (b < 256) { b -= 192; wconv_body(proj_w, wpt, 256, 256,  b & 7, b >> 3, t); }
    else if (b < 512) { b -= 256; wconv_body(ffn_w1, w1t, 256, 1024, b & 7, b >> 3, t); }
    else              { b -= 512; wconv_body(ffn_w2, w2t, 1024, 256, b & 31, b >> 5, t); }
}

// ---------------- K1: BCHW -> token-major transpose + LN1 -> bf16 -------------
// Reduce loop reads ROTATED per sub-lane (R23-verified: 8-way -> ~2-way banks).
__global__ __launch_bounds__(256) void k_ln1(const float* __restrict__ x,
        const float* __restrict__ g, const float* __restrict__ be,
        u16* __restrict__ hln) {
    __shared__ float tile[32][257];
    __shared__ float msh[32], rsh[32];
    int blk = blockIdx.x;            // 16 * 98
    int b   = blk / 98;
    int hw0 = (blk - b * 98) * 32;
    int t   = threadIdx.x;
    int tx  = t & 31, ty = t >> 5;
    for (int c = ty; c < 256; c += 8)
        tile[tx][c] = x[(size_t)(b * 256 + c) * HW + hw0 + tx];
    __syncthreads();
    int row = t >> 3, sub = t & 7;
    float s = 0.f, sq = 0.f;
    for (int i = 0; i < 32; ++i) {
        int cc = sub * 32 + ((i + sub * 4) & 31);
        float v = tile[row][cc]; s += v; sq += v * v;
    }
    for (int o = 4; o; o >>= 1) { s += __shfl_down(s, o, 8); sq += __shfl_down(sq, o, 8); }
    if (sub == 0) {
        float m   = s * (1.f / 256.f);
        float var = sq * (1.f / 256.f) - m * m;
        msh[row] = m; rsh[row] = rsqrtf(var + 1e-5f);
    }
    __syncthreads();
    float gg = g[t], bb = be[t];
    for (int r2 = 0; r2 < 32; ++r2) {
        float v = tile[r2][t];
        hln[(size_t)(b * HW + hw0 + r2) * 256 + t] = f2bu((v - msh[r2]) * rsh[r2] * gg + bb);
    }
}

// ---------------- LN2 + residual: x1 = proj_out + transpose(x); h2 = LN(x1) ---
__global__ __launch_bounds__(256) void k_ln2t(const float* __restrict__ x,
        u16* __restrict__ x1b, const float* __restrict__ g,
        const float* __restrict__ be, u16* __restrict__ h2) {
    __shared__ float tile[32][257];
    __shared__ float msh[32], rsh[32];
    int blk = blockIdx.x;            // 16 * 98
    int b   = blk / 98;
    int hw0 = (blk - b * 98) * 32;
    int t   = threadIdx.x;
    int tx  = t & 31, ty = t >> 5;
    for (int c = ty; c < 256; c += 8)
        tile[tx][c] = x[(size_t)(b * 256 + c) * HW + hw0 + tx];
    __syncthreads();
    size_t base = (size_t)b * HW + hw0;
    for (int r2 = 0; r2 < 32; ++r2) {
        float v = tile[r2][t] + bu2f(x1b[(base + r2) * 256 + t]);
        tile[r2][t] = v;
        x1b[(base + r2) * 256 + t] = f2bu(v);
    }
    __syncthreads();
    int row = t >> 3, sub = t & 7;
    float s = 0.f, sq = 0.f;
    for (int i = 0; i < 32; ++i) {
        int cc = sub * 32 + ((i + sub * 4) & 31);
        float v = tile[row][cc]; s += v; sq += v * v;
    }
    for (int o = 4; o; o >>= 1) { s += __shfl_down(s, o, 8); sq += __shfl_down(sq, o, 8); }
    if (sub == 0) {
        float m   = s * (1.f / 256.f);
        float var = sq * (1.f / 256.f) - m * m;
        msh[row] = m; rsh[row] = rsqrtf(var + 1e-5f);
    }
    __syncthreads();
    float gg = g[t], bb = be[t];
    for (int r2 = 0; r2 < 32; ++r2) {
        float v = tile[r2][t];
        h2[(base + r2) * 256 + t] = f2bu((v - msh[r2]) * rsh[r2] * gg + bb);
    }
}

// ---------------- MFMA GEMM, 256x128 tile, 512 thr (qkv / ffn1) ---------------
// R13-verified loop + T1 XCD grid (verified R17: -28 us).
template<int MODE>
__global__ __launch_bounds__(512) void k_mgemm256(
        const u16* __restrict__ A, const u16* __restrict__ Bt,
        const float* __restrict__ bias, void* __restrict__ Cv, int K, int N,
        int gy) {
    __shared__ __align__(16) u16 As[2][256 * 32];
    __shared__ __align__(16) u16 Bs[2][128 * 32];
    const int swz = xcd_swz(blockIdx.x, gridDim.x);
    const int mb = swz / gy, nb = swz - mb * gy;
    const int m0 = mb * 256, n0 = nb * 128;
    const int t = threadIdx.x, lane = t & 63;
    const int wv = t >> 6, wr = wv >> 1, wc = wv & 1;

    const int kc = (t & 3) ^ ((t >> 3) & 3);
    int ar0 = m0 + (t >> 2), ar1 = m0 + 128 + (t >> 2);
    if (MODE == 0) { ar0 = row2tok(ar0); ar1 = row2tok(ar1); }
    const u16* gA0 = A  + (size_t)ar0 * K + kc * 8;
    const u16* gA1 = A  + (size_t)ar1 * K + kc * 8;
    const u16* gB0 = Bt + (size_t)(n0 + (t >> 2)) * K + kc * 8;

    f32x4 acc[4][4] = {};
    const int ra = wr * 64 + (lane & 15);
    const int rb = wc * 64 + (lane & 15);
    const int kos = (((lane >> 4) ^ (lane >> 1)) & 3) * 8;
    const int nIter = K >> 5;

    gload_lds16(gA0, As[0] + t * 8);
    gload_lds16(gA1, As[0] + 4096 + t * 8);
    gload_lds16(gB0, Bs[0] + t * 8);

    int cur = 0;
    for (int it = 0; it < nIter; ++it) {
        if (it + 1 < nIter) {
            const int k1 = (it + 1) << 5;
            gload_lds16(gA0 + k1, As[cur ^ 1] + t * 8);
            gload_lds16(gA1 + k1, As[cur ^ 1] + 4096 + t * 8);
            gload_lds16(gB0 + k1, Bs[cur ^ 1] + t * 8);
            asm volatile("s_waitcnt vmcnt(3)" ::: "memory");
        } else {
            asm volatile("s_waitcnt vmcnt(0)" ::: "memory");
        }
        __builtin_amdgcn_s_barrier();
        __builtin_amdgcn_sched_barrier(0);
        bf16x8 af[4], bfr[4];
#pragma unroll
        for (int i = 0; i < 4; ++i)
            af[i] = *(const bf16x8*)(As[cur] + (ra + i * 16) * 32 + kos);
#pragma unroll
        for (int j = 0; j < 4; ++j)
            bfr[j] = *(const bf16x8*)(Bs[cur] + (rb + ((j & 1) * 16 + (j >> 1) * 32)) * 32 + kos);
        asm volatile("s_waitcnt lgkmcnt(0)" ::: "memory");
        __builtin_amdgcn_sched_barrier(0);
        __builtin_amdgcn_s_barrier();
#pragma unroll
        for (int i = 0; i < 4; ++i)
#pragma unroll
            for (int j = 0; j < 4; ++j)
                acc[i][j] = __builtin_amdgcn_mfma_f32_16x16x32_bf16(af[i], bfr[j], acc[i][j], 0, 0, 0);
        cur ^= 1;
    }

    const int rowb = m0 + wr * 64 + ((lane >> 4) * 4);
    u16* Cb = (u16*)Cv;
#pragma unroll
    for (int j = 0; j < 4; ++j) {
        int col = n0 + wc * 64 + ((j & 1) * 16 + (j >> 1) * 32) + (lane & 15);
        float bj = bias[col];
#pragma unroll
        for (int i = 0; i < 4; ++i) {
            int rw = rowb + i * 16;
#pragma unroll
            for (int r = 0; r < 4; ++r) {
                float v = acc[i][j][r] + bj;
                if (MODE == 2) v = fmaxf(v, 0.f);
                Cb[(size_t)(rw + r) * N + col] = f2bu(v);
            }
        }
    }
}

// ---------------- MFMA GEMM, 128x128 tile, 256 thr (ffn2) ---------------------
template<int MODE>
__global__ __launch_bounds__(256) void k_mgemm128(
        const u16* __restrict__ A, const u16* __restrict__ Bt,
        const float* __restrict__ bias, void* __restrict__ Cv,
        int K, int N, const void* __restrict__ extra,
        const float* __restrict__ extra2, int grow0, int gy) {
    __shared__ __align__(16) u16 As[2][128 * 32];
    __shared__ __align__(16) u16 Bs[2][128 * 32];
    const int swz = xcd_swz(blockIdx.x, gridDim.x);
    const int mb = swz / gy, nb = swz - mb * gy;
    const int m0 = mb * 128, n0 = nb * 128;
    const int t = threadIdx.x, lane = t & 63;
    const int wv = t >> 6, wr = wv >> 1, wc = wv & 1;

    const int kc = (t & 3) ^ ((t >> 3) & 3);
    const u16* gA0 = A  + (size_t)(m0 + (t >> 2)) * K + kc * 8;
    const u16* gA1 = A  + (size_t)(m0 + 64 + (t >> 2)) * K + kc * 8;
    const u16* gB0 = Bt + (size_t)(n0 + (t >> 2)) * K + kc * 8;
    const u16* gB1 = Bt + (size_t)(n0 + 64 + (t >> 2)) * K + kc * 8;

    f32x4 acc[4][4] = {};
    const int ra = wr * 64 + (lane & 15);
    const int rb = wc * 64 + (lane & 15);
    const int kos = (((lane >> 4) ^ (lane >> 1)) & 3) * 8;
    const int nIter = K >> 5;

    gload_lds16(gA0, As[0] + t * 8);
    gload_lds16(gA1, As[0] + 2048 + t * 8);
    gload_lds16(gB0, Bs[0] + t * 8);
    gload_lds16(gB1, Bs[0] + 2048 + t * 8);

    int cur = 0;
    for (int it = 0; it < nIter; ++it) {
        if (it + 1 < nIter) {
            const int k1 = (it + 1) << 5;
            gload_lds16(gA0 + k1, As[cur ^ 1] + t * 8);
            gload_lds16(gA1 + k1, As[cur ^ 1] + 2048 + t * 8);
            gload_lds16(gB0 + k1, Bs[cur ^ 1] + t * 8);
            gload_lds16(gB1 + k1, Bs[cur ^ 1] + 2048 + t * 8);
            asm volatile("s_waitcnt vmcnt(4)" ::: "memory");
        } else {
            asm volatile("s_waitcnt vmcnt(0)" ::: "memory");
        }
        __builtin_amdgcn_s_barrier();
        __builtin_amdgcn_sched_barrier(0);
        bf16x8 af[4], bfr[4];
#pragma unroll
        for (int i = 0; i < 4; ++i)
            af[i] = *(const bf16x8*)(As[cur] + (ra + i * 16) * 32 + kos);
#pragma unroll
        for (int j = 0; j < 4; ++j)
            bfr[j] = *(const bf16x8*)(Bs[cur] + (rb + j * 16) * 32 + kos);
        asm volatile("s_waitcnt lgkmcnt(0)" ::: "memory");
        __builtin_amdgcn_sched_barrier(0);
        __builtin_amdgcn_s_barrier();
#pragma unroll
        for (int i = 0; i < 4; ++i)
#pragma unroll
            for (int j = 0; j < 4; ++j)
                acc[i][j] = __builtin_amdgcn_mfma_f32_16x16x32_bf16(af[i], bfr[j], acc[i][j], 0, 0, 0);
        cur ^= 1;
    }

    const int colb = n0 + wc * 64 + (lane & 15);
    const int rowb = m0 + wr * 64 + ((lane >> 4) * 4);

    float* C = (float*)Cv;
    const u16* xr = (const u16*)extra;       // x1 bf16
#pragma unroll
    for (int j = 0; j < 4; ++j) {
        int col = colb + j * 16;
        float bj = bias[col], lj = extra2[col];
#pragma unroll
        for (int i = 0; i < 4; ++i) {
            int g  = grow0 + rowb + i * 16;   // 4-row pack never crosses batch
            int b  = g / HW, hw = g - b * HW;
            f32x4 o;
#pragma unroll
            for (int r = 0; r < 4; ++r)
                o[r] = bu2f(xr[(size_t)(g + r) * 256 + col]) + lj * (acc[i][j][r] + bj);
            *(f32x4*)(C + ((size_t)(b * 256 + col)) * HW + hw) = o;
        }
    }
}

// ---------------- fused attention + proj: one BLOCK per window ----------------
// R24-verified structure (swapped QK^T lane-local softmax, tokT table, Pl
// stride 68, PV rows clamped <=48, weights-in-regs proj) + LOAD REORDER:
// qf/kf are issued FIRST, vb scalar gather AFTER. Per m135 vmcnt-oldest
// semantics, QK^T's fragment wait is then vmcnt(32) (qf/kf are the oldest 8
// loads) instead of vmcnt(0) draining all 32 scattered vb loads — vb latency
// now hides under QK^T + softmax + Pl and is only drained at PV.
__global__ __launch_bounds__(512) void k_attnproj(const u16* __restrict__ qkv,
        const u16* __restrict__ wpt, const float* __restrict__ pbias,
        u16* __restrict__ x1b) {
    __shared__ __align__(16) u16 U[8 * LWIN * PLS];   // 53,312 B
    __shared__ int tokT[64];                          // +256 B (53,568 tot)
    const int wv = threadIdx.x >> 6, lane = threadIdx.x & 63;
    const int win = blockIdx.x, head = wv, wi = win & 63;
    const int rowbase = win * LWIN;
    const int g = lane >> 4, c = lane & 15, ko = g * 8;
    const u16* qb = qkv + (size_t)rowbase * 768 + head * 32;
    u16* pl = U + wv * (LWIN * PLS);

    // --- Q/K fragments FIRST (oldest loads -> QK^T waits only on these) ---
    bf16x8 qf[4], kf[4];
#pragma unroll
    for (int i = 0; i < 4; ++i) {
        int r0 = i * 16 + c; if (r0 > 48) r0 = 48;   // clamp: garbage rows unused
        qf[i] = *(const bf16x8*)(qb + (size_t)r0 * 768 + ko);
        kf[i] = *(const bf16x8*)(qb + (size_t)r0 * 768 + 256 + ko);
    }

    // --- V gather AFTER (latency hides under QK^T/softmax/Pl; drained at PV) ---
    bf16x8 vb[2][2];
#pragma unroll
    for (int j2 = 0; j2 < 2; ++j2) {
        int d = j2 * 16 + c;
#pragma unroll
        for (int h = 0; h < 2; ++h)
#pragma unroll
            for (int tt = 0; tt < 8; ++tt) {
                int k = h * 32 + ko + tt;
                u16 val = (k < LWIN) ? qb[(size_t)k * 768 + 512 + d] : (u16)0;
                vb[j2][h][tt] = __builtin_bit_cast(__bf16, val);
            }
    }

    // --- S^T fragments: s[i][j] = K_j^T Q_i -> lane holds qrow=i*16+c,
    //     kcol = j*16 + g*4 + r  (m89 C/D layout with A=kf, B=qf) ---
    f32x4 s[4][4] = {};
    __builtin_amdgcn_s_setprio(1);
#pragma unroll
    for (int i = 0; i < 4; ++i)
#pragma unroll
        for (int j = 0; j < 4; ++j)
            s[i][j] = __builtin_amdgcn_mfma_f32_16x16x32_bf16(kf[j], qf[i], s[i][j], 0, 0, 0);
    __builtin_amdgcn_s_setprio(0);

    // --- masked softmax, lane-local rows ---
    const int wh7 = (wi >> 3) * 7, ww7 = (wi & 7) * 7;
    int idjn[4][4]; bool jokn[4][4];
#pragma unroll
    for (int j = 0; j < 4; ++j)
#pragma unroll
        for (int r = 0; r < 4; ++r) {
            int kcol = j * 16 + g * 4 + r;
            jokn[j][r] = kcol < LWIN;
            int p = jokn[j][r] ? kcol : 48;
            idjn[j][r] = region_of(wh7 + p / 7) * 3 + region_of(ww7 + p % 7);
        }
#pragma unroll
    for (int i = 0; i < 4; ++i) {
        int qrow = i * 16 + c;
        int p = qrow < LWIN ? qrow : 48;
        int idi = region_of(wh7 + p / 7) * 3 + region_of(ww7 + p % 7);
        float mx = -1e30f;
#pragma unroll
        for (int j = 0; j < 4; ++j)
#pragma unroll
            for (int r = 0; r < 4; ++r) {
                float tv = jokn[j][r] ? fmaf(s[i][j][r], 0.17677669529663687f,
                                             (idi == idjn[j][r]) ? 0.f : -100.f)
                                      : -1e30f;
                s[i][j][r] = tv;
                mx = fmaxf(mx, tv);
            }
        mx = fmaxf(mx, __shfl_xor(mx, 16));
        mx = fmaxf(mx, __shfl_xor(mx, 32));
        float ps = 0.f;
#pragma unroll
        for (int j = 0; j < 4; ++j)
#pragma unroll
            for (int r = 0; r < 4; ++r) {
                float e = __expf(s[i][j][r] - mx);
                s[i][j][r] = e; ps += e;
            }
        ps += __shfl_xor(ps, 16);
        ps += __shfl_xor(ps, 32);
        float inv = 1.f / ps;
        if (qrow < LWIN) {
#pragma unroll
            for (int j = 0; j < 4; ++j) {
                ushort4 st{f2bu(s[i][j][0] * inv), f2bu(s[i][j][1] * inv),
                           f2bu(s[i][j][2] * inv), f2bu(s[i][j][3] * inv)};
                *(ushort4*)(pl + qrow * PLS + j * 16 + g * 4) = st;
            }
        }
    }
    // per-wave pl: compiler-inserted lgkmcnt orders write->read within the wave

    // --- O = P V: rows clamped <=48, fragments via two b64 bf16x4 loads ---
    f32x4 o[4][2] = {};
    __builtin_amdgcn_s_setprio(1);
#pragma unroll
    for (int i = 0; i < 4; ++i) {
        int rowA = i * 16 + c; if (rowA > 48) rowA = 48;
        const u16* pr = pl + rowA * PLS + ko;
        bf16x4 a0 = *(const bf16x4*)(pr);
        bf16x4 a1 = *(const bf16x4*)(pr + 4);
        bf16x4 b0 = *(const bf16x4*)(pr + 32);
        bf16x4 b1 = *(const bf16x4*)(pr + 36);
        bf16x8 pa0 = __builtin_shufflevector(a0, a1, 0, 1, 2, 3, 4, 5, 6, 7);
        bf16x8 pa1 = __builtin_shufflevector(b0, b1, 0, 1, 2, 3, 4, 5, 6, 7);
#pragma unroll
        for (int j2 = 0; j2 < 2; ++j2) {
            o[i][j2] = __builtin_amdgcn_mfma_f32_16x16x32_bf16(pa0, vb[j2][0], o[i][j2], 0, 0, 0);
            o[i][j2] = __builtin_amdgcn_mfma_f32_16x16x32_bf16(pa1, vb[j2][1], o[i][j2], 0, 0, 0);
        }
    }
    __builtin_amdgcn_s_setprio(0);

    __syncthreads();        // all waves done reading Pl -> U reusable as o_t

    // --- token table: 49 row2tok calls per BLOCK (was 16 per LANE) ---
    if (threadIdx.x < LWIN)
        tokT[threadIdx.x] = row2tok(rowbase + threadIdx.x);

    // --- weight slice -> registers (no swizzle: regs have no banks) ---
    bf16x8 wreg[8][2];
#pragma unroll
    for (int it = 0; it < 8; ++it)
#pragma unroll
        for (int j2 = 0; j2 < 2; ++j2)
            wreg[it][j2] = *(const bf16x8*)(wpt +
                (size_t)(wv * 32 + j2 * 16 + c) * 256 + it * 32 + ko);

    // --- o_t = U (64 x 264: row stride 528 B -> 2-way banks, free) ---
    u16* o_t = U;
#pragma unroll
    for (int i = 0; i < 4; ++i)
#pragma unroll
        for (int r = 0; r < 4; ++r) {
            int row = i * 16 + g * 4 + r;
            if (row < LWIN) {
#pragma unroll
                for (int j2 = 0; j2 < 2; ++j2)
                    o_t[row * 264 + head * 32 + j2 * 16 + c] = f2bu(o[i][j2][r]);
            }
        }
    __syncthreads();        // o_t + tokT complete (rows >= 49 garbage: discarded)

    // --- proj: 8 x {4 ds_read + 8 MFMA}, no barriers, weights in regs ---
    f32x4 acc2[4][2] = {};
#pragma unroll
    for (int it = 0; it < 8; ++it) {
        bf16x8 af[4];
#pragma unroll
        for (int i = 0; i < 4; ++i)
            af[i] = *(const bf16x8*)(o_t + (i * 16 + c) * 264 + it * 32 + ko);
        __builtin_amdgcn_s_setprio(1);
#pragma unroll
        for (int i = 0; i < 4; ++i)
#pragma unroll
            for (int j2 = 0; j2 < 2; ++j2)
                acc2[i][j2] = __builtin_amdgcn_mfma_f32_16x16x32_bf16(af[i], wreg[it][j2], acc2[i][j2], 0, 0, 0);
        __builtin_amdgcn_s_setprio(0);
    }

    // --- epilogue: scatter to x1b via tokT (LDS), + bias ---
#pragma unroll
    for (int j2 = 0; j2 < 2; ++j2) {
        int col = wv * 32 + j2 * 16 + c;
        float bj = pbias[col];
#pragma unroll
        for (int i = 0; i < 4; ++i)
#pragma unroll
            for (int r = 0; r < 4; ++r) {
                int row = i * 16 + g * 4 + r;
                if (row < LWIN) {
                    int tok = tokT[row];
                    x1b[(size_t)tok * 256 + col] = f2bu(acc2[i][j2][r] + bj);
                }
            }
    }
}

extern "C" void kernel_launch(void* const* d_in, const int* in_sizes, int n_in,
                              void* d_out, int out_size, void* d_ws, size_t ws_size,
                              hipStream_t stream) {
    const float* x      = (const float*)d_in[0];
    const float* ln1_g  = (const float*)d_in[1];
    const float* ln1_b  = (const float*)d_in[2];
    const float* ln2_g  = (const float*)d_in[3];
    const float* ln2_b  = (const float*)d_in[4];
    const float* qkv_w  = (const float*)d_in[5];
    const float* qkv_b  = (const float*)d_in[6];
    const float* proj_w = (const float*)d_in[7];
    const float* proj_b = (const float*)d_in[8];
    const float* ffn_w1 = (const float*)d_in[9];
    const float* ffn_b1 = (const float*)d_in[10];
    const float* ffn_w2 = (const float*)d_in[11];
    const float* ffn_b2 = (const float*)d_in[12];
    const float* lscale = (const float*)d_in[13];

    // workspace: total 104,333,312 B (layout unchanged since R6)
    char* wsb = (char*)d_ws;
    u16* wqt  = (u16*)(wsb);
    u16* wpt  = (u16*)(wsb + 393216);
    u16* w1t  = (u16*)(wsb + 524288);
    u16* w2t  = (u16*)(wsb + 1048576);
    u16* P    = (u16*)(wsb + 1572864);
    char* Qb  = wsb + 27262976;
    u16* qkvb = (u16*)Qb;
    u16* x1b  = (u16*)Qb;
    u16* f1c  = (u16*)(Qb + 25690112);

    k_wconv_all<<<768, 256, 0, stream>>>(qkv_w, wqt, proj_w, wpt, ffn_w1, w1t, ffn_w2, w2t);

    k_ln1<<<16 * 98, 256, 0, stream>>>(x, ln1_g, ln1_b, P);
    // qkv: 196 m-blocks x 6 n-blocks, XCD-swizzled 1-D grid (1176 % 8 == 0)
    k_mgemm256<0><<<1176, 512, 0, stream>>>(P, wqt, qkv_b, qkvb, 256, 768, 6);
    // fused attention + proj -> proj_out (x1b, token-scattered bf16)
    k_attnproj<<<1024, 512, 0, stream>>>(qkvb, wpt, proj_b, x1b);
    // x1 = proj_out + transpose(x) (in-place), h2 = LN2(x1) -> P
    k_ln2t<<<16 * 98, 256, 0, stream>>>(x, x1b, ln2_g, ln2_b, P);
    for (int c = 0; c < 2; ++c) {
        // ffn1: 98 x 8 = 784 (784 % 8 == 0)
        k_mgemm256<2><<<784, 512, 0, stream>>>(P + (size_t)c * FCH * 256, w1t, ffn_b1,
                                               f1c, 256, 1024, 8);
        // ffn2: 196 x 2 = 392 (392 % 8 == 0)
        k_mgemm128<3><<<392, 256, 0, stream>>>(f1c, w2t, ffn_b2, d_out, 1024, 256,
                                               x1b, lscale, c * FCH, 2);
    }
}